// Round 10
// baseline (6551.952 us; speedup 1.0000x reference)
//
#include <hip/hip_runtime.h>
#include <stdint.h>

typedef unsigned short u16;
typedef short bf16x8 __attribute__((ext_vector_type(8)));
typedef float f32x4  __attribute__((ext_vector_type(4)));
typedef unsigned short u16x8 __attribute__((ext_vector_type(8)));
typedef unsigned int   u32x4 __attribute__((ext_vector_type(4)));

__device__ __forceinline__ u16 f2bf(float f) {
  uint32_t u = __float_as_uint(f);
  return (u16)((u + 0x7FFFu + ((u >> 16) & 1u)) >> 16);
}
__device__ __forceinline__ float fsig(float x) {
  x = fminf(fmaxf(x, -30.f), 30.f);
  return __builtin_amdgcn_rcpf(1.f + __builtin_amdgcn_exp2f(-1.44269504088896f * x));
}
__device__ __forceinline__ float ftanhf(float x) {
  x = fminf(fmaxf(x, -10.f), 10.f);
  float e = __builtin_amdgcn_exp2f(2.88539008177793f * x);
  return (e - 1.f) * __builtin_amdgcn_rcpf(e + 1.f);
}

// Coherent (cross-XCD) ops: sc0 sc1 => bypass L1/L2, serialize at MALL.
__device__ __forceinline__ int flag_load(const int* p) {
  int v;
  asm volatile("global_load_dword %0, %1, off sc0 sc1\n\ts_waitcnt vmcnt(0)"
               : "=v"(v) : "v"(p) : "memory");
  return v;
}
__device__ __forceinline__ void flag_store(int* p, int v) {
  asm volatile("global_store_dword %0, %1, off sc0 sc1" :: "v"(p), "v"(v) : "memory");
}
__device__ __forceinline__ uint4 ld_coh_x4(const u16* p) {   // issue only
  uint4 v;
  asm volatile("global_load_dwordx4 %0, %1, off sc0 sc1" : "=v"(v) : "v"(p) : "memory");
  return v;
}
// 16B coherent store; u32x4 ext-vector input (struct inputs don't lower to "v")
__device__ __forceinline__ void st_coh_x4(u16* p, u32x4 v) {
  asm volatile("global_store_dwordx4 %0, %1, off sc0 sc1" :: "v"(p), "v"(v) : "memory");
}
// plain cached 16B load, issue-only (for counted-wait x staging)
__device__ __forceinline__ uint4 ld_x4(const float* p) {
  uint4 v;
  asm volatile("global_load_dwordx4 %0, %1, off" : "=v"(v) : "v"(p) : "memory");
  return v;
}
__device__ __forceinline__ void wait_vm0() {
  asm volatile("s_waitcnt vmcnt(0)" ::: "memory");
}
__device__ __forceinline__ void wait_vm4() {   // wait for all but the newest 4
  asm volatile("s_waitcnt vmcnt(4)" ::: "memory");
}
// Weight-fragment load via volatile asm: result must stay resident (VGPR/AGPR).
__device__ __forceinline__ bf16x8 pin_frag(const u16* p) {
  uint4 v;
  asm volatile("global_load_dwordx4 %0, %1, off" : "=v"(v) : "v"(p));
  return __builtin_bit_cast(bf16x8, v);
}
// Fast poll: no sleep (detection latency = one coherent-load RT), bounded.
__device__ __forceinline__ void poll_flag(const int* fp, int target) {
  int spins = 0;
  while (flag_load(fp) < target) {
    if (++spins > 300000) break;   // bounded: broken sync -> wrong answer, not hang
  }
}

// ---------------------------------------------------------------------------
// prep: f32 weights -> bf16 MFMA fragment layout, gate-permuted columns;
// zeroes the per-wave flag arrays. n'=4*unit+gate => orig col = gate*512+unit.
// ---------------------------------------------------------------------------
__global__ void prep_kernel(const float* __restrict__ Wf, const float* __restrict__ Uf, const float* __restrict__ bf,
                            const float* __restrict__ Wb, const float* __restrict__ Ub, const float* __restrict__ bb,
                            const float* __restrict__ Wd, const float* __restrict__ Ud, const float* __restrict__ bd,
                            const float* __restrict__ Wo,
                            u16* __restrict__ encF, u16* __restrict__ encB,
                            u16* __restrict__ udF, u16* __restrict__ wdF, u16* __restrict__ woF,
                            float* __restrict__ biasF, float* __restrict__ biasB, float* __restrict__ biasD,
                            int* __restrict__ flagsE, int* __restrict__ flagsD)
{
  constexpr int NC_ENC = 128 * 24 * 64;
  constexpr int NC_UD  = 128 * 16 * 64;
  constexpr int NC_WD  = 128 * 32 * 64;
  constexpr int NC_WO  = 16 * 16 * 64;
  constexpr int B1 = 2 * NC_ENC;
  constexpr int B2 = B1 + NC_UD;
  constexpr int B3 = B2 + NC_WD;
  constexpr int B4 = B3 + NC_WO;
  constexpr int B5 = B4 + 768;
  constexpr int B6 = B5 + 128;      // flagsE: 16g*64 ints / 8
  constexpr int TOTAL = B6 + 64;    // flagsD: 8g*64 ints / 8

  for (int idx = blockIdx.x * 256 + threadIdx.x; idx < TOTAL; idx += gridDim.x * 256) {
    if (idx < B1) {
      int d = idx / NC_ENC;
      int r = idx - d * NC_ENC;
      int ntg = r / 1536;
      int rem = r - ntg * 1536;
      int kt = rem >> 6, lane = rem & 63;
      int np = ntg * 16 + (lane & 15);
      int col = (np & 3) * 512 + (np >> 2);
      int kb = kt * 32 + (lane >> 4) * 8;
      const float* W = d ? Wb : Wf;
      const float* U = d ? Ub : Uf;
      u16* dst = (d ? encB : encF) + (size_t)r * 8;
      if (kb < 256) {
        const float* s = W + (size_t)kb * 2048 + col;
#pragma unroll
        for (int e = 0; e < 8; ++e) dst[e] = f2bf(s[(size_t)e * 2048]);
      } else {
        const float* s = U + (size_t)(kb - 256) * 2048 + col;
#pragma unroll
        for (int e = 0; e < 8; ++e) dst[e] = f2bf(s[(size_t)e * 2048]);
      }
    } else if (idx < B2) {
      int r = idx - B1;
      int ntg = r / 1024;
      int rem = r - ntg * 1024;
      int kt = rem >> 6, lane = rem & 63;
      int np = ntg * 16 + (lane & 15);
      int col = (np & 3) * 512 + (np >> 2);
      int kb = kt * 32 + (lane >> 4) * 8;
      const float* s = Ud + (size_t)kb * 2048 + col;
      u16* dst = udF + (size_t)r * 8;
#pragma unroll
      for (int e = 0; e < 8; ++e) dst[e] = f2bf(s[(size_t)e * 2048]);
    } else if (idx < B3) {
      int r = idx - B2;
      int ntg = r / 2048;
      int rem = r - ntg * 2048;
      int kt = rem >> 6, lane = rem & 63;
      int np = ntg * 16 + (lane & 15);
      int col = (np & 3) * 512 + (np >> 2);
      int kb = kt * 32 + (lane >> 4) * 8;
      const float* s = Wd + (size_t)kb * 2048 + col;
      u16* dst = wdF + (size_t)r * 8;
#pragma unroll
      for (int e = 0; e < 8; ++e) dst[e] = f2bf(s[(size_t)e * 2048]);
    } else if (idx < B4) {
      int r = idx - B3;
      int nt = r / 1024;
      int rem = r - nt * 1024;
      int kt = rem >> 6, lane = rem & 63;
      int col = nt * 16 + (lane & 15);
      int kb = kt * 32 + (lane >> 4) * 8;
      const float* s = Wo + (size_t)kb * 256 + col;
      u16* dst = woF + (size_t)r * 8;
#pragma unroll
      for (int e = 0; e < 8; ++e) dst[e] = f2bf(s[(size_t)e * 256]);
    } else if (idx < B5) {
      int r = idx - B4;
      int which = r >> 8;
      int j0 = (r & 255) * 8;
      const float* src = (which == 0) ? bf : (which == 1) ? bb : bd;
      float* dstb = (which == 0) ? biasF : (which == 1) ? biasB : biasD;
#pragma unroll
      for (int e = 0; e < 8; ++e) {
        int np = j0 + e;
        dstb[np] = src[(np & 3) * 512 + (np >> 2)];
      }
    } else if (idx < B6) {
      int r = idx - B5;
#pragma unroll
      for (int e = 0; e < 8; ++e) flagsE[r * 8 + e] = 0;
    } else {
      int r = idx - B6;
#pragma unroll
      for (int e = 0; e < 8; ++e) flagsD[r * 8 + e] = 0;
    }
  }
}

// ---------------------------------------------------------------------------
// h exchange (per group, per slot of 8192 u16):
//   chunk(b,row) = 8 u16 at u16 offset b*128 + row*8; b = producer wave id
//   (wgi*4+w). PER-WAVE flags (64/group): a wave stores its 16 chunks (one
//   dwordx4/lane<16 => ONE wave-level vmcnt op), waits vmcnt(0) (vmcnt is a
//   wave counter), lane0 raises flag — no WG barrier on the release path.
//   Consumer thread tid: b = tid>>2, rows (tid&3)*4+k at hs+8k, polls the
//   single flag of producer wave b.
// ---------------------------------------------------------------------------

// encoder: 16 groups (dir=g>>3, rows (g&7)*16..+15), 16 WGs/group, 1 WG/CU.
__global__ __launch_bounds__(256, 1) void enc_kernel(
    const float* __restrict__ x,
    const u16* __restrict__ encF, const u16* __restrict__ encB,
    const float* __restrict__ biasF, const float* __restrict__ biasB,
    float* __restrict__ latent, u16* __restrict__ hbuf, int* __restrict__ flags)
{
  const int bid = blockIdx.x;
  const int g   = bid & 15;
  const int wgi = bid >> 4;
  const int dir = g >> 3;
  const int rowBase = (g & 7) * 16;
  const int tid = threadIdx.x;
  const int lane = tid & 63;
  const int wave = tid >> 6;
  const int l15 = lane & 15;
  const int lk  = lane >> 4;

  __shared__ __attribute__((aligned(16))) u16   xlds[2][16][264];
  __shared__ __attribute__((aligned(16))) u16   Alds[16][520];
  __shared__ __attribute__((aligned(16))) float zlds[4][2][16][20];
  __shared__ __attribute__((aligned(16))) u16   hlds[4][16][8];

  const u16* wsrc = dir ? encB : encF;
  bf16x8 Breg[2][24];
#pragma unroll
  for (int n = 0; n < 2; ++n) {
    const int ntg = wgi * 8 + wave * 2 + n;
    const u16* fb = wsrc + (size_t)(ntg * 1536 + lane) * 8;
#pragma unroll
    for (int kt = 0; kt < 24; ++kt)
      Breg[n][kt] = pin_frag(fb + kt * 512);
  }
  wait_vm0();
  __builtin_amdgcn_sched_barrier(0);

  const float* bias = dir ? biasB : biasF;
  float bias_r[2];
  bias_r[0] = bias[(wgi * 8 + wave * 2 + 0) * 16 + l15];
  bias_r[1] = bias[(wgi * 8 + wave * 2 + 1) * 16 + l15];

  u16* myH = hbuf + (size_t)g * 16384;
  int* myFlags = flags + g * 64;                // per-wave flags, 64/group
  const int* myPollFlag = &myFlags[tid >> 2];   // producer WAVE of this thread's chunks
  const int myFlagIdx = wgi * 4 + wave;
  const int xr = tid >> 4, xc = tid & 15;       // x staging assignment
  const int cb = tid >> 2;                      // consumer unit-block 0..63
  const int cr0 = (tid & 3) * 4;                // consumer first row

  // prologue: stage x_{t(0)} into xlds[0]
  {
    const int t0 = dir ? 1023 : 0;
    const float* xp = x + ((size_t)(rowBase + xr) * 1024 + t0) * 256 + xc * 16;
    float4 f0 = *(const float4*)xp;
    float4 f1 = *(const float4*)(xp + 4);
    float4 f2 = *(const float4*)(xp + 8);
    float4 f3 = *(const float4*)(xp + 12);
    u16x8 a, b;
    a[0]=f2bf(f0.x); a[1]=f2bf(f0.y); a[2]=f2bf(f0.z); a[3]=f2bf(f0.w);
    a[4]=f2bf(f1.x); a[5]=f2bf(f1.y); a[6]=f2bf(f1.z); a[7]=f2bf(f1.w);
    b[0]=f2bf(f2.x); b[1]=f2bf(f2.y); b[2]=f2bf(f2.z); b[3]=f2bf(f2.w);
    b[4]=f2bf(f3.x); b[5]=f2bf(f3.y); b[6]=f2bf(f3.z); b[7]=f2bf(f3.w);
    *(u16x8*)&xlds[0][xr][xc * 16] = a;
    *(u16x8*)&xlds[0][xr][xc * 16 + 8] = b;
  }
  __syncthreads();

  float cc0 = 0.f, cc1 = 0.f;

  for (int s = 0; s < 1024; ++s) {
    // ---- P1: x-part MFMA from xlds[s&1] ----
    f32x4 acc0 = {bias_r[0], bias_r[0], bias_r[0], bias_r[0]};
    f32x4 acc1 = {bias_r[1], bias_r[1], bias_r[1], bias_r[1]};
#pragma unroll
    for (int kt = 0; kt < 8; ++kt) {
      bf16x8 av = *(const bf16x8*)&xlds[s & 1][l15][kt * 32 + lk * 8];
      acc0 = __builtin_amdgcn_mfma_f32_16x16x32_bf16(av, Breg[0][kt], acc0, 0, 0, 0);
      acc1 = __builtin_amdgcn_mfma_f32_16x16x32_bf16(av, Breg[1][kt], acc1, 0, 0, 0);
    }

    const int sn = (s + 1 < 1024) ? s + 1 : 1023;
    const int tn = dir ? (1023 - sn) : sn;
    const float* xp = x + ((size_t)(rowBase + xr) * 1024 + tn) * 256 + xc * 16;
    uint4 xq0, xq1, xq2, xq3;

    // ---- P2: per-wave flag poll -> h loads, then x loads, counted wait ----
    if (s > 0) {
      poll_flag(myPollFlag, s);
      const u16* hs = myH + ((s - 1) & 1) * 8192 + cb * 128 + cr0 * 8;
      uint4 h0 = ld_coh_x4(hs);
      uint4 h1 = ld_coh_x4(hs + 8);
      uint4 h2 = ld_coh_x4(hs + 16);
      uint4 h3 = ld_coh_x4(hs + 24);
      xq0 = ld_x4(xp);           // next-step x: drains later, off the h path
      xq1 = ld_x4(xp + 4);
      xq2 = ld_x4(xp + 8);
      xq3 = ld_x4(xp + 12);
      wait_vm4();                // waits only the 4 h loads (oldest)
      __builtin_amdgcn_sched_barrier(0);
      *(uint4*)&Alds[cr0][cb * 8]     = h0;
      *(uint4*)&Alds[cr0 + 1][cb * 8] = h1;
      *(uint4*)&Alds[cr0 + 2][cb * 8] = h2;
      *(uint4*)&Alds[cr0 + 3][cb * 8] = h3;
      __syncthreads();
#pragma unroll
      for (int kt = 0; kt < 16; ++kt) {
        bf16x8 av = *(const bf16x8*)&Alds[l15][kt * 32 + lk * 8];
        acc0 = __builtin_amdgcn_mfma_f32_16x16x32_bf16(av, Breg[0][kt + 8], acc0, 0, 0, 0);
        acc1 = __builtin_amdgcn_mfma_f32_16x16x32_bf16(av, Breg[1][kt + 8], acc1, 0, 0, 0);
      }
    } else {
      xq0 = ld_x4(xp);
      xq1 = ld_x4(xp + 4);
      xq2 = ld_x4(xp + 8);
      xq3 = ld_x4(xp + 12);
    }

    // ---- P3: transpose gates (wave-local LDS), activations ----
#pragma unroll
    for (int r = 0; r < 4; ++r) {
      zlds[wave][0][lk * 4 + r][l15] = acc0[r];
      zlds[wave][1][lk * 4 + r][l15] = acc1[r];
    }
    asm volatile("s_waitcnt lgkmcnt(0)" ::: "memory");
    float4 g0 = *(const float4*)&zlds[wave][0][l15][lk * 4];
    float4 g1 = *(const float4*)&zlds[wave][1][l15][lk * 4];
    float hv0, hv1;
    { float iv = fsig(g0.x), fv = fsig(g0.y), gg = ftanhf(g0.z), ov = fsig(g0.w);
      cc0 = fv * cc0 + iv * gg;  hv0 = ov * ftanhf(cc0); }
    { float iv = fsig(g1.x), fv = fsig(g1.y), gg = ftanhf(g1.z), ov = fsig(g1.w);
      cc1 = fv * cc1 + iv * gg;  hv1 = ov * ftanhf(cc1); }

    // ---- P4: gather + 16B store + wave-local drain + per-wave flag ----
    if (s < 1023) {
      hlds[wave][l15][lk]     = f2bf(hv0);
      hlds[wave][l15][lk + 4] = f2bf(hv1);
      asm volatile("s_waitcnt lgkmcnt(0)" ::: "memory");
      if (lane < 16) {
        const u32x4 c = *(const u32x4*)&hlds[wave][lane][0];
        u16* hw = myH + (s & 1) * 8192 + (wgi * 4 + wave) * 128 + lane * 8;
        st_coh_x4(hw, c);
      }
    } else {
      float* lp = latent + (size_t)(rowBase + l15) * 1024 + dir * 512 + wgi * 32 + wave * 8 + lk;
      lp[0] = hv0;
      lp[4] = hv1;
    }
    wait_vm0();                  // drains this wave's h store (+x loads, done)
    __builtin_amdgcn_sched_barrier(0);
    if (lane == 0 && s < 1023) flag_store(&myFlags[myFlagIdx], s + 1);

    // ---- P5: convert + store x for next step (in the flag's shadow) ----
    {
      float4 f0 = __builtin_bit_cast(float4, xq0);
      float4 f1 = __builtin_bit_cast(float4, xq1);
      float4 f2 = __builtin_bit_cast(float4, xq2);
      float4 f3 = __builtin_bit_cast(float4, xq3);
      u16x8 a, b;
      a[0]=f2bf(f0.x); a[1]=f2bf(f0.y); a[2]=f2bf(f0.z); a[3]=f2bf(f0.w);
      a[4]=f2bf(f1.x); a[5]=f2bf(f1.y); a[6]=f2bf(f1.z); a[7]=f2bf(f1.w);
      b[0]=f2bf(f2.x); b[1]=f2bf(f2.y); b[2]=f2bf(f2.z); b[3]=f2bf(f2.w);
      b[4]=f2bf(f3.x); b[5]=f2bf(f3.y); b[6]=f2bf(f3.z); b[7]=f2bf(f3.w);
      *(u16x8*)&xlds[(s + 1) & 1][xr][xc * 16] = a;
      *(u16x8*)&xlds[(s + 1) & 1][xr][xc * 16 + 8] = b;
    }
    __syncthreads();   // protects xlds next-buf and Alds rewrite
  }
}

// ---------------------------------------------------------------------------
// decoder: 8 groups x 16 rows, 16 WGs/group (128 WGs). xwd in regs; per-wave
// flags; Alds double-buffered => NO loop-end barrier (dense out-stores drain
// in the poll's shadow).
// ---------------------------------------------------------------------------
__global__ __launch_bounds__(256, 1) void dec_kernel(
    const float* __restrict__ latent,
    const u16* __restrict__ udF, const u16* __restrict__ wdF, const u16* __restrict__ woF,
    const float* __restrict__ biasD, const float* __restrict__ bo,
    float* __restrict__ out, u16* __restrict__ hbuf, int* __restrict__ flags)
{
  const int bid = blockIdx.x;      // 0..127
  const int g   = bid & 7;
  const int wgi = bid >> 3;        // 0..15
  const int rowBase = g * 16;
  const int tid = threadIdx.x;
  const int lane = tid & 63;
  const int wave = tid >> 6;
  const int l15 = lane & 15;
  const int lk  = lane >> 4;

  __shared__ __attribute__((aligned(16))) u16   Llds[16][1032];
  __shared__ __attribute__((aligned(16))) u16   Alds[2][16][520];
  __shared__ __attribute__((aligned(16))) float zlds[4][2][16][20];
  __shared__ __attribute__((aligned(16))) u16   hlds[4][16][8];

#pragma unroll
  for (int c8 = 0; c8 < 8; ++c8) {
    const int idx = tid + c8 * 256;
    const int rr = idx >> 7, cf = idx & 127;
    const float* lp = latent + (size_t)(rowBase + rr) * 1024 + cf * 8;
    float4 v0 = *(const float4*)lp;
    float4 v1 = *(const float4*)(lp + 4);
    u16x8 tv;
    tv[0]=f2bf(v0.x); tv[1]=f2bf(v0.y); tv[2]=f2bf(v0.z); tv[3]=f2bf(v0.w);
    tv[4]=f2bf(v1.x); tv[5]=f2bf(v1.y); tv[6]=f2bf(v1.z); tv[7]=f2bf(v1.w);
    *(u16x8*)&Llds[rr][cf * 8] = tv;
  }
  __syncthreads();

  f32x4 xwd[2];
#pragma unroll
  for (int n = 0; n < 2; ++n) {
    const int ntg = wgi * 8 + wave * 2 + n;
    const float br = biasD[ntg * 16 + l15];
    f32x4 xw = {br, br, br, br};
    const u16* wf = wdF + (size_t)(ntg * 2048 + lane) * 8;
#pragma unroll
    for (int kt = 0; kt < 32; ++kt) {
      bf16x8 b = *(const bf16x8*)(wf + kt * 512);
      bf16x8 a = *(const bf16x8*)&Llds[l15][kt * 32 + lk * 8];
      xw = __builtin_amdgcn_mfma_f32_16x16x32_bf16(a, b, xw, 0, 0, 0);
    }
    xwd[n] = xw;
  }

  bf16x8 Bu[2][16];
#pragma unroll
  for (int n = 0; n < 2; ++n) {
    const int ntg = wgi * 8 + wave * 2 + n;
    const u16* ub = udF + (size_t)(ntg * 1024 + lane) * 8;
#pragma unroll
    for (int kt = 0; kt < 16; ++kt)
      Bu[n][kt] = pin_frag(ub + kt * 512);
  }
  bf16x8 Bo[16];
  if (wave == 0) {
    const u16* ob = woF + (size_t)(wgi * 1024 + lane) * 8;
#pragma unroll
    for (int kt = 0; kt < 16; ++kt)
      Bo[kt] = pin_frag(ob + kt * 512);
  }
  wait_vm0();
  __builtin_amdgcn_sched_barrier(0);
  const float bo_r = bo[wgi * 16 + l15];

  u16* myH = hbuf + (size_t)g * 16384;
  int* myFlags = flags + g * 64;                // per-wave flags
  const int* myPollFlag = &myFlags[tid >> 2];
  const int myFlagIdx = wgi * 4 + wave;
  const int cb = tid >> 2;
  const int cr0 = (tid & 3) * 4;

  float cc0 = 0.f, cc1 = 0.f;

  for (int t = 0; t < 1024; ++t) {
    f32x4 acc0 = xwd[0], acc1 = xwd[1];

    if (t > 0) {
      poll_flag(myPollFlag, t);
      const u16* hs = myH + ((t - 1) & 1) * 8192 + cb * 128 + cr0 * 8;
      uint4 h0 = ld_coh_x4(hs);
      uint4 h1 = ld_coh_x4(hs + 8);
      uint4 h2 = ld_coh_x4(hs + 16);
      uint4 h3 = ld_coh_x4(hs + 24);
      wait_vm0();                // also drains last step's dense out-stores (old)
      __builtin_amdgcn_sched_barrier(0);
      *(uint4*)&Alds[t & 1][cr0][cb * 8]     = h0;
      *(uint4*)&Alds[t & 1][cr0 + 1][cb * 8] = h1;
      *(uint4*)&Alds[t & 1][cr0 + 2][cb * 8] = h2;
      *(uint4*)&Alds[t & 1][cr0 + 3][cb * 8] = h3;
      __syncthreads();
#pragma unroll
      for (int kt = 0; kt < 16; ++kt) {
        bf16x8 av = *(const bf16x8*)&Alds[t & 1][l15][kt * 32 + lk * 8];
        acc0 = __builtin_amdgcn_mfma_f32_16x16x32_bf16(av, Bu[0][kt], acc0, 0, 0, 0);
        acc1 = __builtin_amdgcn_mfma_f32_16x16x32_bf16(av, Bu[1][kt], acc1, 0, 0, 0);
      }
    }

#pragma unroll
    for (int r = 0; r < 4; ++r) {
      zlds[wave][0][lk * 4 + r][l15] = acc0[r];
      zlds[wave][1][lk * 4 + r][l15] = acc1[r];
    }
    asm volatile("s_waitcnt lgkmcnt(0)" ::: "memory");
    float4 g0 = *(const float4*)&zlds[wave][0][l15][lk * 4];
    float4 g1 = *(const float4*)&zlds[wave][1][l15][lk * 4];
    float hv0, hv1;
    { float iv = fsig(g0.x), fv = fsig(g0.y), gg = ftanhf(g0.z), ov = fsig(g0.w);
      cc0 = fv * cc0 + iv * gg;  hv0 = ov * ftanhf(cc0); }
    { float iv = fsig(g1.x), fv = fsig(g1.y), gg = ftanhf(g1.z), ov = fsig(g1.w);
      cc1 = fv * cc1 + iv * gg;  hv1 = ov * ftanhf(cc1); }

    // gather + 16B coherent store + wave-local drain + per-wave flag
    {
      hlds[wave][l15][lk]     = f2bf(hv0);
      hlds[wave][l15][lk + 4] = f2bf(hv1);
      asm volatile("s_waitcnt lgkmcnt(0)" ::: "memory");
      if (lane < 16) {
        const u32x4 c = *(const u32x4*)&hlds[wave][lane][0];
        u16* hw = myH + (t & 1) * 8192 + (wgi * 4 + wave) * 128 + lane * 8;
        st_coh_x4(hw, c);
      }
      wait_vm0();
      __builtin_amdgcn_sched_barrier(0);
      if (lane == 0) flag_store(&myFlags[myFlagIdx], t + 1);
    }

    // fused Dense for out[:, t-1, :] — after release; drains next poll
    if (t > 0 && wave == 0) {
      f32x4 od = {bo_r, bo_r, bo_r, bo_r};
#pragma unroll
      for (int kt = 0; kt < 16; ++kt) {
        bf16x8 a = *(const bf16x8*)&Alds[t & 1][l15][kt * 32 + lk * 8];
        od = __builtin_amdgcn_mfma_f32_16x16x32_bf16(a, Bo[kt], od, 0, 0, 0);
      }
#pragma unroll
      for (int r = 0; r < 4; ++r)
        out[((size_t)(rowBase + lk * 4 + r) * 1024 + (t - 1)) * 256 + wgi * 16 + l15] = od[r];
    }
    // no loop-end barrier: Alds is double-buffered; zlds/hlds are wave-local
  }

  // out[:, 1023, :] — stage h_1023 into Alds[0] (dense(1023) reads Alds[1])
  poll_flag(myPollFlag, 1024);
  {
    const u16* hs = myH + 8192 + cb * 128 + cr0 * 8;   // slot 1 = h_1023
    uint4 h0 = ld_coh_x4(hs);
    uint4 h1 = ld_coh_x4(hs + 8);
    uint4 h2 = ld_coh_x4(hs + 16);
    uint4 h3 = ld_coh_x4(hs + 24);
    wait_vm0();
    __builtin_amdgcn_sched_barrier(0);
    *(uint4*)&Alds[0][cr0][cb * 8]     = h0;
    *(uint4*)&Alds[0][cr0 + 1][cb * 8] = h1;
    *(uint4*)&Alds[0][cr0 + 2][cb * 8] = h2;
    *(uint4*)&Alds[0][cr0 + 3][cb * 8] = h3;
    __syncthreads();
    if (wave == 0) {
      f32x4 od = {bo_r, bo_r, bo_r, bo_r};
#pragma unroll
      for (int kt = 0; kt < 16; ++kt) {
        bf16x8 a = *(const bf16x8*)&Alds[0][l15][kt * 32 + lk * 8];
        od = __builtin_amdgcn_mfma_f32_16x16x32_bf16(a, Bo[kt], od, 0, 0, 0);
      }
#pragma unroll
      for (int r = 0; r < 4; ++r)
        out[((size_t)(rowBase + lk * 4 + r) * 1024 + 1023) * 256 + wgi * 16 + l15] = od[r];
    }
  }
}

// ---------------------------------------------------------------------------
extern "C" void kernel_launch(void* const* d_in, const int* in_sizes, int n_in,
                              void* d_out, int out_size, void* d_ws, size_t ws_size,
                              hipStream_t stream)
{
  const float* x  = (const float*)d_in[0];
  const float* Wf = (const float*)d_in[1];
  const float* Uf = (const float*)d_in[2];
  const float* bf = (const float*)d_in[3];
  const float* Wb = (const float*)d_in[4];
  const float* Ub = (const float*)d_in[5];
  const float* bb = (const float*)d_in[6];
  const float* Wd = (const float*)d_in[7];
  const float* Ud = (const float*)d_in[8];
  const float* bd = (const float*)d_in[9];
  const float* Wo = (const float*)d_in[10];
  const float* bo = (const float*)d_in[11];

  if (ws_size < 14182400) return;

  char* ws = (char*)d_ws;
  u16*  encF   = (u16*)(ws + 0);
  u16*  encB   = (u16*)(ws + 3145728);
  u16*  udF    = (u16*)(ws + 6291456);
  u16*  wdF    = (u16*)(ws + 8388608);
  u16*  woF    = (u16*)(ws + 12582912);
  float* biasF = (float*)(ws + 12845056);
  float* biasB = (float*)(ws + 12853248);
  float* biasD = (float*)(ws + 12861440);
  float* latent= (float*)(ws + 12869632);
  u16*  hbufE  = (u16*)(ws + 13393920);   // 16 groups * 16384 u16 = 512KB
  u16*  hbufD  = (u16*)(ws + 13918208);   // 8 groups * 16384 u16 = 256KB
  // enc per-wave flags (4KB) OVERLAY the first 4KB of hbufD: enc and dec are
  // stream-ordered (dec launches after enc completes), and dec rewrites the
  // region before any dec read (chunk writes precede flag-gated reads).
  int*  flagsE = (int*)(ws + 13918208);   // 1024 ints (16 groups * 64 waves)
  int*  flagsD = (int*)(ws + 14180352);   // 512 ints  (8 groups * 64 waves)

  prep_kernel<<<256, 256, 0, stream>>>(Wf, Uf, bf, Wb, Ub, bb, Wd, Ud, bd, Wo,
                                       encF, encB, udF, wdF, woF,
                                       biasF, biasB, biasD, flagsE, flagsD);
  enc_kernel<<<256, 256, 0, stream>>>(x, encF, encB, biasF, biasB, latent, hbufE, flagsE);
  dec_kernel<<<128, 256, 0, stream>>>(latent, udF, wdF, woF, biasD, bo,
                                      (float*)d_out, hbufD, flagsD);
}

// Round 12
// 6531.633 us; speedup vs baseline: 1.0031x; 1.0031x over previous
//
#include <hip/hip_runtime.h>
#include <stdint.h>

typedef unsigned short u16;
typedef short bf16x8 __attribute__((ext_vector_type(8)));
typedef float f32x4  __attribute__((ext_vector_type(4)));
typedef unsigned short u16x8 __attribute__((ext_vector_type(8)));
typedef unsigned int   u32x4 __attribute__((ext_vector_type(4)));

__device__ __forceinline__ u16 f2bf(float f) {
  uint32_t u = __float_as_uint(f);
  return (u16)((u + 0x7FFFu + ((u >> 16) & 1u)) >> 16);
}
__device__ __forceinline__ float fsig(float x) {
  x = fminf(fmaxf(x, -30.f), 30.f);
  return __builtin_amdgcn_rcpf(1.f + __builtin_amdgcn_exp2f(-1.44269504088896f * x));
}
__device__ __forceinline__ float ftanhf(float x) {
  x = fminf(fmaxf(x, -10.f), 10.f);
  float e = __builtin_amdgcn_exp2f(2.88539008177793f * x);
  return (e - 1.f) * __builtin_amdgcn_rcpf(e + 1.f);
}

// Coherent (cross-XCD) ops: sc0 sc1 => bypass L1/L2, serialize at MALL.
// r11 lesson: sc0-only (XCD-L2) exchange does NOT work — MALL path only.
__device__ __forceinline__ int flag_load(const int* p) {
  int v;
  asm volatile("global_load_dword %0, %1, off sc0 sc1\n\ts_waitcnt vmcnt(0)"
               : "=v"(v) : "v"(p) : "memory");
  return v;
}
__device__ __forceinline__ void flag_store(int* p, int v) {
  asm volatile("global_store_dword %0, %1, off sc0 sc1" :: "v"(p), "v"(v) : "memory");
}
__device__ __forceinline__ uint4 ld_coh_x4(const u16* p) {   // issue only
  uint4 v;
  asm volatile("global_load_dwordx4 %0, %1, off sc0 sc1" : "=v"(v) : "v"(p) : "memory");
  return v;
}
// 16B coherent store; u32x4 ext-vector input (struct inputs don't lower to "v")
__device__ __forceinline__ void st_coh_x4(u16* p, u32x4 v) {
  asm volatile("global_store_dwordx4 %0, %1, off sc0 sc1" :: "v"(p), "v"(v) : "memory");
}
// plain cached 16B load, issue-only (for counted-wait x staging)
__device__ __forceinline__ uint4 ld_x4(const float* p) {
  uint4 v;
  asm volatile("global_load_dwordx4 %0, %1, off" : "=v"(v) : "v"(p) : "memory");
  return v;
}
__device__ __forceinline__ void wait_vm0() {
  asm volatile("s_waitcnt vmcnt(0)" ::: "memory");
}
__device__ __forceinline__ void wait_vm4() {   // wait for all but the newest 4
  asm volatile("s_waitcnt vmcnt(4)" ::: "memory");
}
// Weight-fragment load via volatile asm: result must stay resident (VGPR/AGPR).
__device__ __forceinline__ bf16x8 pin_frag(const u16* p) {
  uint4 v;
  asm volatile("global_load_dwordx4 %0, %1, off" : "=v"(v) : "v"(p));
  return __builtin_bit_cast(bf16x8, v);
}
// Paced poll: s_sleep(1) between iterations (r10: unpaced spinning congests
// the MALL and inflates every handoff RT).
__device__ __forceinline__ void poll_flag(const int* fp, int target) {
  int spins = 0;
  while (flag_load(fp) < target) {
    __builtin_amdgcn_s_sleep(1);
    if (++spins > 200000) break;   // bounded: broken sync -> wrong answer, not hang
  }
}

// ---------------------------------------------------------------------------
// prep: f32 weights -> bf16 MFMA fragment layout, gate-permuted columns;
// zeroes the per-wave flag arrays. n'=4*unit+gate => orig col = gate*512+unit.
// ---------------------------------------------------------------------------
__global__ void prep_kernel(const float* __restrict__ Wf, const float* __restrict__ Uf, const float* __restrict__ bf,
                            const float* __restrict__ Wb, const float* __restrict__ Ub, const float* __restrict__ bb,
                            const float* __restrict__ Wd, const float* __restrict__ Ud, const float* __restrict__ bd,
                            const float* __restrict__ Wo,
                            u16* __restrict__ encF, u16* __restrict__ encB,
                            u16* __restrict__ udF, u16* __restrict__ wdF, u16* __restrict__ woF,
                            float* __restrict__ biasF, float* __restrict__ biasB, float* __restrict__ biasD,
                            int* __restrict__ flagsE, int* __restrict__ flagsD)
{
  constexpr int NC_ENC = 128 * 24 * 64;
  constexpr int NC_UD  = 128 * 16 * 64;
  constexpr int NC_WD  = 128 * 32 * 64;
  constexpr int NC_WO  = 16 * 16 * 64;
  constexpr int B1 = 2 * NC_ENC;
  constexpr int B2 = B1 + NC_UD;
  constexpr int B3 = B2 + NC_WD;
  constexpr int B4 = B3 + NC_WO;
  constexpr int B5 = B4 + 768;
  constexpr int B6 = B5 + 128;      // flagsE: 16g*64 ints / 8
  constexpr int TOTAL = B6 + 64;    // flagsD: 8g*64 ints / 8

  for (int idx = blockIdx.x * 256 + threadIdx.x; idx < TOTAL; idx += gridDim.x * 256) {
    if (idx < B1) {
      int d = idx / NC_ENC;
      int r = idx - d * NC_ENC;
      int ntg = r / 1536;
      int rem = r - ntg * 1536;
      int kt = rem >> 6, lane = rem & 63;
      int np = ntg * 16 + (lane & 15);
      int col = (np & 3) * 512 + (np >> 2);
      int kb = kt * 32 + (lane >> 4) * 8;
      const float* W = d ? Wb : Wf;
      const float* U = d ? Ub : Uf;
      u16* dst = (d ? encB : encF) + (size_t)r * 8;
      if (kb < 256) {
        const float* s = W + (size_t)kb * 2048 + col;
#pragma unroll
        for (int e = 0; e < 8; ++e) dst[e] = f2bf(s[(size_t)e * 2048]);
      } else {
        const float* s = U + (size_t)(kb - 256) * 2048 + col;
#pragma unroll
        for (int e = 0; e < 8; ++e) dst[e] = f2bf(s[(size_t)e * 2048]);
      }
    } else if (idx < B2) {
      int r = idx - B1;
      int ntg = r / 1024;
      int rem = r - ntg * 1024;
      int kt = rem >> 6, lane = rem & 63;
      int np = ntg * 16 + (lane & 15);
      int col = (np & 3) * 512 + (np >> 2);
      int kb = kt * 32 + (lane >> 4) * 8;
      const float* s = Ud + (size_t)kb * 2048 + col;
      u16* dst = udF + (size_t)r * 8;
#pragma unroll
      for (int e = 0; e < 8; ++e) dst[e] = f2bf(s[(size_t)e * 2048]);
    } else if (idx < B3) {
      int r = idx - B2;
      int ntg = r / 2048;
      int rem = r - ntg * 2048;
      int kt = rem >> 6, lane = rem & 63;
      int np = ntg * 16 + (lane & 15);
      int col = (np & 3) * 512 + (np >> 2);
      int kb = kt * 32 + (lane >> 4) * 8;
      const float* s = Wd + (size_t)kb * 2048 + col;
      u16* dst = wdF + (size_t)r * 8;
#pragma unroll
      for (int e = 0; e < 8; ++e) dst[e] = f2bf(s[(size_t)e * 2048]);
    } else if (idx < B4) {
      int r = idx - B3;
      int nt = r / 1024;
      int rem = r - nt * 1024;
      int kt = rem >> 6, lane = rem & 63;
      int col = nt * 16 + (lane & 15);
      int kb = kt * 32 + (lane >> 4) * 8;
      const float* s = Wo + (size_t)kb * 256 + col;
      u16* dst = woF + (size_t)r * 8;
#pragma unroll
      for (int e = 0; e < 8; ++e) dst[e] = f2bf(s[(size_t)e * 256]);
    } else if (idx < B5) {
      int r = idx - B4;
      int which = r >> 8;
      int j0 = (r & 255) * 8;
      const float* src = (which == 0) ? bf : (which == 1) ? bb : bd;
      float* dstb = (which == 0) ? biasF : (which == 1) ? biasB : biasD;
#pragma unroll
      for (int e = 0; e < 8; ++e) {
        int np = j0 + e;
        dstb[np] = src[(np & 3) * 512 + (np >> 2)];
      }
    } else if (idx < B6) {
      int r = idx - B5;
#pragma unroll
      for (int e = 0; e < 8; ++e) flagsE[r * 8 + e] = 0;
    } else {
      int r = idx - B6;
#pragma unroll
      for (int e = 0; e < 8; ++e) flagsD[r * 8 + e] = 0;
    }
  }
}

// ---------------------------------------------------------------------------
// h exchange (per group, per slot of 8192 u16):
//   chunk(b,row) = 8 u16 at u16 offset b*128 + row*8; b = producer wave id
//   (wgi*4+w). Per-wave flags (64/group): a wave stores its 16 chunks (one
//   dwordx4/lane<16), waits vmcnt(0) (vmcnt is a per-wave counter), lane0
//   raises its flag — no WG barrier on the release path. Consumer thread
//   tid: b = tid>>2, rows (tid&3)*4+k at hs+8k, polls producer wave b's flag.
// ---------------------------------------------------------------------------

// encoder: 16 groups (dir=g>>3, rows (g&7)*16..+15), 16 WGs/group, 1 WG/CU.
__global__ __launch_bounds__(256, 1) void enc_kernel(
    const float* __restrict__ x,
    const u16* __restrict__ encF, const u16* __restrict__ encB,
    const float* __restrict__ biasF, const float* __restrict__ biasB,
    float* __restrict__ latent, u16* __restrict__ hbuf, int* __restrict__ flags)
{
  const int bid = blockIdx.x;
  const int g   = bid & 15;
  const int wgi = bid >> 4;
  const int dir = g >> 3;
  const int rowBase = (g & 7) * 16;
  const int tid = threadIdx.x;
  const int lane = tid & 63;
  const int wave = tid >> 6;
  const int l15 = lane & 15;
  const int lk  = lane >> 4;

  __shared__ __attribute__((aligned(16))) u16   xlds[2][16][264];
  __shared__ __attribute__((aligned(16))) u16   Alds[16][520];
  __shared__ __attribute__((aligned(16))) float zlds[4][2][16][20];
  __shared__ __attribute__((aligned(16))) u16   hlds[4][16][8];

  const u16* wsrc = dir ? encB : encF;
  bf16x8 Breg[2][24];
#pragma unroll
  for (int n = 0; n < 2; ++n) {
    const int ntg = wgi * 8 + wave * 2 + n;
    const u16* fb = wsrc + (size_t)(ntg * 1536 + lane) * 8;
#pragma unroll
    for (int kt = 0; kt < 24; ++kt)
      Breg[n][kt] = pin_frag(fb + kt * 512);
  }
  wait_vm0();
  __builtin_amdgcn_sched_barrier(0);

  const float* bias = dir ? biasB : biasF;
  float bias_r[2];
  bias_r[0] = bias[(wgi * 8 + wave * 2 + 0) * 16 + l15];
  bias_r[1] = bias[(wgi * 8 + wave * 2 + 1) * 16 + l15];

  u16* myH = hbuf + (size_t)g * 16384;
  int* myFlags = flags + g * 64;                // per-wave flags, 64/group
  const int* myPollFlag = &myFlags[tid >> 2];   // producer WAVE of this thread's chunks
  const int myFlagIdx = wgi * 4 + wave;
  const int xr = tid >> 4, xc = tid & 15;       // x staging assignment
  const int cb = tid >> 2;                      // consumer unit-block 0..63
  const int cr0 = (tid & 3) * 4;                // consumer first row

  // prologue: stage x_{t(0)} into xlds[0]
  {
    const int t0 = dir ? 1023 : 0;
    const float* xp = x + ((size_t)(rowBase + xr) * 1024 + t0) * 256 + xc * 16;
    float4 f0 = *(const float4*)xp;
    float4 f1 = *(const float4*)(xp + 4);
    float4 f2 = *(const float4*)(xp + 8);
    float4 f3 = *(const float4*)(xp + 12);
    u16x8 a, b;
    a[0]=f2bf(f0.x); a[1]=f2bf(f0.y); a[2]=f2bf(f0.z); a[3]=f2bf(f0.w);
    a[4]=f2bf(f1.x); a[5]=f2bf(f1.y); a[6]=f2bf(f1.z); a[7]=f2bf(f1.w);
    b[0]=f2bf(f2.x); b[1]=f2bf(f2.y); b[2]=f2bf(f2.z); b[3]=f2bf(f2.w);
    b[4]=f2bf(f3.x); b[5]=f2bf(f3.y); b[6]=f2bf(f3.z); b[7]=f2bf(f3.w);
    *(u16x8*)&xlds[0][xr][xc * 16] = a;
    *(u16x8*)&xlds[0][xr][xc * 16 + 8] = b;
  }
  __syncthreads();

  float cc0 = 0.f, cc1 = 0.f;

  for (int s = 0; s < 1024; ++s) {
    // ---- P1: x-part MFMA from xlds[s&1] ----
    f32x4 acc0 = {bias_r[0], bias_r[0], bias_r[0], bias_r[0]};
    f32x4 acc1 = {bias_r[1], bias_r[1], bias_r[1], bias_r[1]};
#pragma unroll
    for (int kt = 0; kt < 8; ++kt) {
      bf16x8 av = *(const bf16x8*)&xlds[s & 1][l15][kt * 32 + lk * 8];
      acc0 = __builtin_amdgcn_mfma_f32_16x16x32_bf16(av, Breg[0][kt], acc0, 0, 0, 0);
      acc1 = __builtin_amdgcn_mfma_f32_16x16x32_bf16(av, Breg[1][kt], acc1, 0, 0, 0);
    }

    const int sn = (s + 1 < 1024) ? s + 1 : 1023;
    const int tn = dir ? (1023 - sn) : sn;
    const float* xp = x + ((size_t)(rowBase + xr) * 1024 + tn) * 256 + xc * 16;
    uint4 xq0, xq1, xq2, xq3;

    // ---- P2: per-wave flag poll -> h loads, then x loads, counted wait ----
    if (s > 0) {
      poll_flag(myPollFlag, s);
      const u16* hs = myH + ((s - 1) & 1) * 8192 + cb * 128 + cr0 * 8;
      uint4 h0 = ld_coh_x4(hs);
      uint4 h1 = ld_coh_x4(hs + 8);
      uint4 h2 = ld_coh_x4(hs + 16);
      uint4 h3 = ld_coh_x4(hs + 24);
      xq0 = ld_x4(xp);           // next-step x: drains later, off the h path
      xq1 = ld_x4(xp + 4);
      xq2 = ld_x4(xp + 8);
      xq3 = ld_x4(xp + 12);
      wait_vm4();                // waits only the 4 h loads (oldest)
      __builtin_amdgcn_sched_barrier(0);
      *(uint4*)&Alds[cr0][cb * 8]     = h0;
      *(uint4*)&Alds[cr0 + 1][cb * 8] = h1;
      *(uint4*)&Alds[cr0 + 2][cb * 8] = h2;
      *(uint4*)&Alds[cr0 + 3][cb * 8] = h3;
      __syncthreads();
#pragma unroll
      for (int kt = 0; kt < 16; ++kt) {
        bf16x8 av = *(const bf16x8*)&Alds[l15][kt * 32 + lk * 8];
        acc0 = __builtin_amdgcn_mfma_f32_16x16x32_bf16(av, Breg[0][kt + 8], acc0, 0, 0, 0);
        acc1 = __builtin_amdgcn_mfma_f32_16x16x32_bf16(av, Breg[1][kt + 8], acc1, 0, 0, 0);
      }
    } else {
      xq0 = ld_x4(xp);
      xq1 = ld_x4(xp + 4);
      xq2 = ld_x4(xp + 8);
      xq3 = ld_x4(xp + 12);
    }

    // ---- P3: transpose gates (wave-local LDS), activations ----
#pragma unroll
    for (int r = 0; r < 4; ++r) {
      zlds[wave][0][lk * 4 + r][l15] = acc0[r];
      zlds[wave][1][lk * 4 + r][l15] = acc1[r];
    }
    asm volatile("s_waitcnt lgkmcnt(0)" ::: "memory");
    float4 g0 = *(const float4*)&zlds[wave][0][l15][lk * 4];
    float4 g1 = *(const float4*)&zlds[wave][1][l15][lk * 4];
    float hv0, hv1;
    { float iv = fsig(g0.x), fv = fsig(g0.y), gg = ftanhf(g0.z), ov = fsig(g0.w);
      cc0 = fv * cc0 + iv * gg;  hv0 = ov * ftanhf(cc0); }
    { float iv = fsig(g1.x), fv = fsig(g1.y), gg = ftanhf(g1.z), ov = fsig(g1.w);
      cc1 = fv * cc1 + iv * gg;  hv1 = ov * ftanhf(cc1); }

    // ---- P4: gather + 16B store + wave-local drain + per-wave flag ----
    if (s < 1023) {
      hlds[wave][l15][lk]     = f2bf(hv0);
      hlds[wave][l15][lk + 4] = f2bf(hv1);
      asm volatile("s_waitcnt lgkmcnt(0)" ::: "memory");
      if (lane < 16) {
        const u32x4 c = *(const u32x4*)&hlds[wave][lane][0];
        u16* hw = myH + (s & 1) * 8192 + (wgi * 4 + wave) * 128 + lane * 8;
        st_coh_x4(hw, c);
      }
    } else {
      float* lp = latent + (size_t)(rowBase + l15) * 1024 + dir * 512 + wgi * 32 + wave * 8 + lk;
      lp[0] = hv0;
      lp[4] = hv1;
    }
    wait_vm0();                  // drains this wave's h store (+x loads, done)
    __builtin_amdgcn_sched_barrier(0);
    if (lane == 0 && s < 1023) flag_store(&myFlags[myFlagIdx], s + 1);

    // ---- P5: convert + store x for next step (in the flag's shadow) ----
    {
      float4 f0 = __builtin_bit_cast(float4, xq0);
      float4 f1 = __builtin_bit_cast(float4, xq1);
      float4 f2 = __builtin_bit_cast(float4, xq2);
      float4 f3 = __builtin_bit_cast(float4, xq3);
      u16x8 a, b;
      a[0]=f2bf(f0.x); a[1]=f2bf(f0.y); a[2]=f2bf(f0.z); a[3]=f2bf(f0.w);
      a[4]=f2bf(f1.x); a[5]=f2bf(f1.y); a[6]=f2bf(f1.z); a[7]=f2bf(f1.w);
      b[0]=f2bf(f2.x); b[1]=f2bf(f2.y); b[2]=f2bf(f2.z); b[3]=f2bf(f2.w);
      b[4]=f2bf(f3.x); b[5]=f2bf(f3.y); b[6]=f2bf(f3.z); b[7]=f2bf(f3.w);
      *(u16x8*)&xlds[(s + 1) & 1][xr][xc * 16] = a;
      *(u16x8*)&xlds[(s + 1) & 1][xr][xc * 16 + 8] = b;
    }
    __syncthreads();   // protects xlds next-buf and Alds rewrite
  }
}

// ---------------------------------------------------------------------------
// decoder: 8 groups x 16 rows, 16 WGs/group (128 WGs). xwd in regs; per-wave
// flags; Alds double-buffered => no loop-end barrier (dense out-stores drain
// in the poll's shadow).
// ---------------------------------------------------------------------------
__global__ __launch_bounds__(256, 1) void dec_kernel(
    const float* __restrict__ latent,
    const u16* __restrict__ udF, const u16* __restrict__ wdF, const u16* __restrict__ woF,
    const float* __restrict__ biasD, const float* __restrict__ bo,
    float* __restrict__ out, u16* __restrict__ hbuf, int* __restrict__ flags)
{
  const int bid = blockIdx.x;      // 0..127
  const int g   = bid & 7;
  const int wgi = bid >> 3;        // 0..15
  const int rowBase = g * 16;
  const int tid = threadIdx.x;
  const int lane = tid & 63;
  const int wave = tid >> 6;
  const int l15 = lane & 15;
  const int lk  = lane >> 4;

  __shared__ __attribute__((aligned(16))) u16   Llds[16][1032];
  __shared__ __attribute__((aligned(16))) u16   Alds[2][16][520];
  __shared__ __attribute__((aligned(16))) float zlds[4][2][16][20];
  __shared__ __attribute__((aligned(16))) u16   hlds[4][16][8];

#pragma unroll
  for (int c8 = 0; c8 < 8; ++c8) {
    const int idx = tid + c8 * 256;
    const int rr = idx >> 7, cf = idx & 127;
    const float* lp = latent + (size_t)(rowBase + rr) * 1024 + cf * 8;
    float4 v0 = *(const float4*)lp;
    float4 v1 = *(const float4*)(lp + 4);
    u16x8 tv;
    tv[0]=f2bf(v0.x); tv[1]=f2bf(v0.y); tv[2]=f2bf(v0.z); tv[3]=f2bf(v0.w);
    tv[4]=f2bf(v1.x); tv[5]=f2bf(v1.y); tv[6]=f2bf(v1.z); tv[7]=f2bf(v1.w);
    *(u16x8*)&Llds[rr][cf * 8] = tv;
  }
  __syncthreads();

  f32x4 xwd[2];
#pragma unroll
  for (int n = 0; n < 2; ++n) {
    const int ntg = wgi * 8 + wave * 2 + n;
    const float br = biasD[ntg * 16 + l15];
    f32x4 xw = {br, br, br, br};
    const u16* wf = wdF + (size_t)(ntg * 2048 + lane) * 8;
#pragma unroll
    for (int kt = 0; kt < 32; ++kt) {
      bf16x8 b = *(const bf16x8*)(wf + kt * 512);
      bf16x8 a = *(const bf16x8*)&Llds[l15][kt * 32 + lk * 8];
      xw = __builtin_amdgcn_mfma_f32_16x16x32_bf16(a, b, xw, 0, 0, 0);
    }
    xwd[n] = xw;
  }

  bf16x8 Bu[2][16];
#pragma unroll
  for (int n = 0; n < 2; ++n) {
    const int ntg = wgi * 8 + wave * 2 + n;
    const u16* ub = udF + (size_t)(ntg * 1024 + lane) * 8;
#pragma unroll
    for (int kt = 0; kt < 16; ++kt)
      Bu[n][kt] = pin_frag(ub + kt * 512);
  }
  bf16x8 Bo[16];
  if (wave == 0) {
    const u16* ob = woF + (size_t)(wgi * 1024 + lane) * 8;
#pragma unroll
    for (int kt = 0; kt < 16; ++kt)
      Bo[kt] = pin_frag(ob + kt * 512);
  }
  wait_vm0();
  __builtin_amdgcn_sched_barrier(0);
  const float bo_r = bo[wgi * 16 + l15];

  u16* myH = hbuf + (size_t)g * 16384;
  int* myFlags = flags + g * 64;                // per-wave flags
  const int* myPollFlag = &myFlags[tid >> 2];
  const int myFlagIdx = wgi * 4 + wave;
  const int cb = tid >> 2;
  const int cr0 = (tid & 3) * 4;

  float cc0 = 0.f, cc1 = 0.f;

  for (int t = 0; t < 1024; ++t) {
    f32x4 acc0 = xwd[0], acc1 = xwd[1];

    if (t > 0) {
      poll_flag(myPollFlag, t);
      const u16* hs = myH + ((t - 1) & 1) * 8192 + cb * 128 + cr0 * 8;
      uint4 h0 = ld_coh_x4(hs);
      uint4 h1 = ld_coh_x4(hs + 8);
      uint4 h2 = ld_coh_x4(hs + 16);
      uint4 h3 = ld_coh_x4(hs + 24);
      wait_vm0();                // also drains last step's dense out-stores
      __builtin_amdgcn_sched_barrier(0);
      *(uint4*)&Alds[t & 1][cr0][cb * 8]     = h0;
      *(uint4*)&Alds[t & 1][cr0 + 1][cb * 8] = h1;
      *(uint4*)&Alds[t & 1][cr0 + 2][cb * 8] = h2;
      *(uint4*)&Alds[t & 1][cr0 + 3][cb * 8] = h3;
      __syncthreads();
#pragma unroll
      for (int kt = 0; kt < 16; ++kt) {
        bf16x8 av = *(const bf16x8*)&Alds[t & 1][l15][kt * 32 + lk * 8];
        acc0 = __builtin_amdgcn_mfma_f32_16x16x32_bf16(av, Bu[0][kt], acc0, 0, 0, 0);
        acc1 = __builtin_amdgcn_mfma_f32_16x16x32_bf16(av, Bu[1][kt], acc1, 0, 0, 0);
      }
    }

#pragma unroll
    for (int r = 0; r < 4; ++r) {
      zlds[wave][0][lk * 4 + r][l15] = acc0[r];
      zlds[wave][1][lk * 4 + r][l15] = acc1[r];
    }
    asm volatile("s_waitcnt lgkmcnt(0)" ::: "memory");
    float4 g0 = *(const float4*)&zlds[wave][0][l15][lk * 4];
    float4 g1 = *(const float4*)&zlds[wave][1][l15][lk * 4];
    float hv0, hv1;
    { float iv = fsig(g0.x), fv = fsig(g0.y), gg = ftanhf(g0.z), ov = fsig(g0.w);
      cc0 = fv * cc0 + iv * gg;  hv0 = ov * ftanhf(cc0); }
    { float iv = fsig(g1.x), fv = fsig(g1.y), gg = ftanhf(g1.z), ov = fsig(g1.w);
      cc1 = fv * cc1 + iv * gg;  hv1 = ov * ftanhf(cc1); }

    // gather + 16B store + wave-local drain + per-wave flag
    {
      hlds[wave][l15][lk]     = f2bf(hv0);
      hlds[wave][l15][lk + 4] = f2bf(hv1);
      asm volatile("s_waitcnt lgkmcnt(0)" ::: "memory");
      if (lane < 16) {
        const u32x4 c = *(const u32x4*)&hlds[wave][lane][0];
        u16* hw = myH + (t & 1) * 8192 + (wgi * 4 + wave) * 128 + lane * 8;
        st_coh_x4(hw, c);
      }
      wait_vm0();
      __builtin_amdgcn_sched_barrier(0);
      if (lane == 0) flag_store(&myFlags[myFlagIdx], t + 1);
    }

    // fused Dense for out[:, t-1, :] — after release; drains next poll
    if (t > 0 && wave == 0) {
      f32x4 od = {bo_r, bo_r, bo_r, bo_r};
#pragma unroll
      for (int kt = 0; kt < 16; ++kt) {
        bf16x8 a = *(const bf16x8*)&Alds[t & 1][l15][kt * 32 + lk * 8];
        od = __builtin_amdgcn_mfma_f32_16x16x32_bf16(a, Bo[kt], od, 0, 0, 0);
      }
#pragma unroll
      for (int r = 0; r < 4; ++r)
        out[((size_t)(rowBase + lk * 4 + r) * 1024 + (t - 1)) * 256 + wgi * 16 + l15] = od[r];
    }
    // no loop-end barrier: Alds double-buffered; zlds/hlds are wave-local
  }

  // out[:, 1023, :] — stage h_1023 into Alds[0] (dense(1023) reads Alds[1])
  poll_flag(myPollFlag, 1024);
  {
    const u16* hs = myH + 8192 + cb * 128 + cr0 * 8;   // slot 1 = h_1023
    uint4 h0 = ld_coh_x4(hs);
    uint4 h1 = ld_coh_x4(hs + 8);
    uint4 h2 = ld_coh_x4(hs + 16);
    uint4 h3 = ld_coh_x4(hs + 24);
    wait_vm0();
    __builtin_amdgcn_sched_barrier(0);
    *(uint4*)&Alds[0][cr0][cb * 8]     = h0;
    *(uint4*)&Alds[0][cr0 + 1][cb * 8] = h1;
    *(uint4*)&Alds[0][cr0 + 2][cb * 8] = h2;
    *(uint4*)&Alds[0][cr0 + 3][cb * 8] = h3;
    __syncthreads();
    if (wave == 0) {
      f32x4 od = {bo_r, bo_r, bo_r, bo_r};
#pragma unroll
      for (int kt = 0; kt < 16; ++kt) {
        bf16x8 a = *(const bf16x8*)&Alds[0][l15][kt * 32 + lk * 8];
        od = __builtin_amdgcn_mfma_f32_16x16x32_bf16(a, Bo[kt], od, 0, 0, 0);
      }
#pragma unroll
      for (int r = 0; r < 4; ++r)
        out[((size_t)(rowBase + lk * 4 + r) * 1024 + 1023) * 256 + wgi * 16 + l15] = od[r];
    }
  }
}

// ---------------------------------------------------------------------------
extern "C" void kernel_launch(void* const* d_in, const int* in_sizes, int n_in,
                              void* d_out, int out_size, void* d_ws, size_t ws_size,
                              hipStream_t stream)
{
  const float* x  = (const float*)d_in[0];
  const float* Wf = (const float*)d_in[1];
  const float* Uf = (const float*)d_in[2];
  const float* bf = (const float*)d_in[3];
  const float* Wb = (const float*)d_in[4];
  const float* Ub = (const float*)d_in[5];
  const float* bb = (const float*)d_in[6];
  const float* Wd = (const float*)d_in[7];
  const float* Ud = (const float*)d_in[8];
  const float* bd = (const float*)d_in[9];
  const float* Wo = (const float*)d_in[10];
  const float* bo = (const float*)d_in[11];

  if (ws_size < 14182400) return;

  char* ws = (char*)d_ws;
  u16*  encF   = (u16*)(ws + 0);
  u16*  encB   = (u16*)(ws + 3145728);
  u16*  udF    = (u16*)(ws + 6291456);
  u16*  wdF    = (u16*)(ws + 8388608);
  u16*  woF    = (u16*)(ws + 12582912);
  float* biasF = (float*)(ws + 12845056);
  float* biasB = (float*)(ws + 12853248);
  float* biasD = (float*)(ws + 12861440);
  float* latent= (float*)(ws + 12869632);
  u16*  hbufE  = (u16*)(ws + 13393920);   // 16 groups * 16384 u16 = 512KB
  u16*  hbufD  = (u16*)(ws + 13918208);   // 8 groups * 16384 u16 = 256KB
  // flagsE (4KB) overlays hbufD[0..4K): enc and dec are stream-ordered, and
  // dec rewrites the region (flag-gated) before any dec read. (r10: passed.)
  int*  flagsE = (int*)(ws + 13918208);   // 1024 ints (16 groups * 64 waves)
  int*  flagsD = (int*)(ws + 14180352);   // 512 ints  (8 groups * 64 waves)

  prep_kernel<<<256, 256, 0, stream>>>(Wf, Uf, bf, Wb, Ub, bb, Wd, Ud, bd, Wo,
                                       encF, encB, udF, wdF, woF,
                                       biasF, biasB, biasD, flagsE, flagsD);
  enc_kernel<<<256, 256, 0, stream>>>(x, encF, encB, biasF, biasB, latent, hbufE, flagsE);
  dec_kernel<<<128, 256, 0, stream>>>(latent, udF, wdF, woF, biasD, bo,
                                      (float*)d_out, hbufD, flagsD);
}

// Round 13
// 5929.902 us; speedup vs baseline: 1.1049x; 1.1015x over previous
//
#include <hip/hip_runtime.h>
#include <stdint.h>

typedef unsigned short u16;
typedef short bf16x8 __attribute__((ext_vector_type(8)));
typedef float f32x4  __attribute__((ext_vector_type(4)));
typedef unsigned short u16x8 __attribute__((ext_vector_type(8)));
typedef unsigned int   u32x4 __attribute__((ext_vector_type(4)));

__device__ __forceinline__ u16 f2bf(float f) {
  uint32_t u = __float_as_uint(f);
  return (u16)((u + 0x7FFFu + ((u >> 16) & 1u)) >> 16);
}
__device__ __forceinline__ float fsig(float x) {
  x = fminf(fmaxf(x, -30.f), 30.f);
  return __builtin_amdgcn_rcpf(1.f + __builtin_amdgcn_exp2f(-1.44269504088896f * x));
}
__device__ __forceinline__ float ftanhf(float x) {
  x = fminf(fmaxf(x, -10.f), 10.f);
  float e = __builtin_amdgcn_exp2f(2.88539008177793f * x);
  return (e - 1.f) * __builtin_amdgcn_rcpf(e + 1.f);
}

// Coherent (cross-XCD) ops: sc0 sc1 => bypass L1/L2, serialize at MALL.
// r11: sc0-only (XCD-L2) exchange does NOT work. r12: per-wave flags lose to
// WG-level flags (flag-traffic congestion). This is the r9 best-known config.
__device__ __forceinline__ int flag_load(const int* p) {
  int v;
  asm volatile("global_load_dword %0, %1, off sc0 sc1\n\ts_waitcnt vmcnt(0)"
               : "=v"(v) : "v"(p) : "memory");
  return v;
}
__device__ __forceinline__ void flag_store(int* p, int v) {
  asm volatile("global_store_dword %0, %1, off sc0 sc1" :: "v"(p), "v"(v) : "memory");
}
__device__ __forceinline__ uint4 ld_coh_x4(const u16* p) {   // issue only
  uint4 v;
  asm volatile("global_load_dwordx4 %0, %1, off sc0 sc1" : "=v"(v) : "v"(p) : "memory");
  return v;
}
// 16B coherent store; u32x4 ext-vector input (struct inputs don't lower to "v")
__device__ __forceinline__ void st_coh_x4(u16* p, u32x4 v) {
  asm volatile("global_store_dwordx4 %0, %1, off sc0 sc1" :: "v"(p), "v"(v) : "memory");
}
// plain cached 16B load, issue-only (for counted-wait x staging)
__device__ __forceinline__ uint4 ld_x4(const float* p) {
  uint4 v;
  asm volatile("global_load_dwordx4 %0, %1, off" : "=v"(v) : "v"(p) : "memory");
  return v;
}
__device__ __forceinline__ void wait_vm0() {
  asm volatile("s_waitcnt vmcnt(0)" ::: "memory");
}
__device__ __forceinline__ void wait_vm4() {   // wait for all but the newest 4
  asm volatile("s_waitcnt vmcnt(4)" ::: "memory");
}
// Weight-fragment load via volatile asm: result must stay resident (VGPR/AGPR).
__device__ __forceinline__ bf16x8 pin_frag(const u16* p) {
  uint4 v;
  asm volatile("global_load_dwordx4 %0, %1, off" : "=v"(v) : "v"(p));
  return __builtin_bit_cast(bf16x8, v);
}
// Paced poll (s_sleep(1) between iterations; unpaced spinning congests MALL).
__device__ __forceinline__ void poll_flag(const int* fp, int target) {
  int spins = 0;
  while (flag_load(fp) < target) {
    __builtin_amdgcn_s_sleep(1);
    if (++spins > 200000) break;   // bounded: broken sync -> wrong answer, not hang
  }
}

// ---------------------------------------------------------------------------
// prep: f32 weights -> bf16 MFMA fragment layout, gate-permuted columns;
// zeroes the 512 flag ints. n' = 4*unit + gate => original col = gate*512+unit.
// ---------------------------------------------------------------------------
__global__ void prep_kernel(const float* __restrict__ Wf, const float* __restrict__ Uf, const float* __restrict__ bf,
                            const float* __restrict__ Wb, const float* __restrict__ Ub, const float* __restrict__ bb,
                            const float* __restrict__ Wd, const float* __restrict__ Ud, const float* __restrict__ bd,
                            const float* __restrict__ Wo,
                            u16* __restrict__ encF, u16* __restrict__ encB,
                            u16* __restrict__ udF, u16* __restrict__ wdF, u16* __restrict__ woF,
                            float* __restrict__ biasF, float* __restrict__ biasB, float* __restrict__ biasD,
                            int* __restrict__ flagsAll)
{
  constexpr int NC_ENC = 128 * 24 * 64;
  constexpr int NC_UD  = 128 * 16 * 64;
  constexpr int NC_WD  = 128 * 32 * 64;
  constexpr int NC_WO  = 16 * 16 * 64;
  constexpr int B1 = 2 * NC_ENC;
  constexpr int B2 = B1 + NC_UD;
  constexpr int B3 = B2 + NC_WD;
  constexpr int B4 = B3 + NC_WO;
  constexpr int B5 = B4 + 768;
  constexpr int TOTAL = B5 + 64;

  for (int idx = blockIdx.x * 256 + threadIdx.x; idx < TOTAL; idx += gridDim.x * 256) {
    if (idx < B1) {
      int d = idx / NC_ENC;
      int r = idx - d * NC_ENC;
      int ntg = r / 1536;
      int rem = r - ntg * 1536;
      int kt = rem >> 6, lane = rem & 63;
      int np = ntg * 16 + (lane & 15);
      int col = (np & 3) * 512 + (np >> 2);
      int kb = kt * 32 + (lane >> 4) * 8;
      const float* W = d ? Wb : Wf;
      const float* U = d ? Ub : Uf;
      u16* dst = (d ? encB : encF) + (size_t)r * 8;
      if (kb < 256) {
        const float* s = W + (size_t)kb * 2048 + col;
#pragma unroll
        for (int e = 0; e < 8; ++e) dst[e] = f2bf(s[(size_t)e * 2048]);
      } else {
        const float* s = U + (size_t)(kb - 256) * 2048 + col;
#pragma unroll
        for (int e = 0; e < 8; ++e) dst[e] = f2bf(s[(size_t)e * 2048]);
      }
    } else if (idx < B2) {
      int r = idx - B1;
      int ntg = r / 1024;
      int rem = r - ntg * 1024;
      int kt = rem >> 6, lane = rem & 63;
      int np = ntg * 16 + (lane & 15);
      int col = (np & 3) * 512 + (np >> 2);
      int kb = kt * 32 + (lane >> 4) * 8;
      const float* s = Ud + (size_t)kb * 2048 + col;
      u16* dst = udF + (size_t)r * 8;
#pragma unroll
      for (int e = 0; e < 8; ++e) dst[e] = f2bf(s[(size_t)e * 2048]);
    } else if (idx < B3) {
      int r = idx - B2;
      int ntg = r / 2048;
      int rem = r - ntg * 2048;
      int kt = rem >> 6, lane = rem & 63;
      int np = ntg * 16 + (lane & 15);
      int col = (np & 3) * 512 + (np >> 2);
      int kb = kt * 32 + (lane >> 4) * 8;
      const float* s = Wd + (size_t)kb * 2048 + col;
      u16* dst = wdF + (size_t)r * 8;
#pragma unroll
      for (int e = 0; e < 8; ++e) dst[e] = f2bf(s[(size_t)e * 2048]);
    } else if (idx < B4) {
      int r = idx - B3;
      int nt = r / 1024;
      int rem = r - nt * 1024;
      int kt = rem >> 6, lane = rem & 63;
      int col = nt * 16 + (lane & 15);
      int kb = kt * 32 + (lane >> 4) * 8;
      const float* s = Wo + (size_t)kb * 256 + col;
      u16* dst = woF + (size_t)r * 8;
#pragma unroll
      for (int e = 0; e < 8; ++e) dst[e] = f2bf(s[(size_t)e * 256]);
    } else if (idx < B5) {
      int r = idx - B4;
      int which = r >> 8;
      int j0 = (r & 255) * 8;
      const float* src = (which == 0) ? bf : (which == 1) ? bb : bd;
      float* dstb = (which == 0) ? biasF : (which == 1) ? biasB : biasD;
#pragma unroll
      for (int e = 0; e < 8; ++e) {
        int np = j0 + e;
        dstb[np] = src[(np & 3) * 512 + (np >> 2)];
      }
    } else {
      int r = idx - B5;
#pragma unroll
      for (int e = 0; e < 8; ++e) flagsAll[r * 8 + e] = 0;
    }
  }
}

// ---------------------------------------------------------------------------
// h exchange layout (per group, per slot of 8192 u16):
//   chunk(b,row) = 8 u16 (units b*8..b*8+7, batch row) at u16 offset b*128+row*8.
//   Producer: wave w of WG wgi owns b = wgi*4+w -> 16 chunks, 256B contiguous,
//   one dwordx4 store per lane<16.
//   Consumer thread tid: b = tid>>2, rows (tid&3)*4+k (k=0..3) at
//   hs, hs+8, hs+16, hs+24 -> all 4 chunks from producer WG tid>>4 (WG flag).
// ---------------------------------------------------------------------------

// encoder: 16 groups (dir=g>>3, rows (g&7)*16..+15), 16 WGs/group, 1 WG/CU.
__global__ __launch_bounds__(256, 1) void enc_kernel(
    const float* __restrict__ x,
    const u16* __restrict__ encF, const u16* __restrict__ encB,
    const float* __restrict__ biasF, const float* __restrict__ biasB,
    float* __restrict__ latent, u16* __restrict__ hbuf, int* __restrict__ flags)
{
  const int bid = blockIdx.x;
  const int g   = bid & 15;
  const int wgi = bid >> 4;
  const int dir = g >> 3;
  const int rowBase = (g & 7) * 16;
  const int tid = threadIdx.x;
  const int lane = tid & 63;
  const int wave = tid >> 6;
  const int l15 = lane & 15;
  const int lk  = lane >> 4;

  __shared__ __attribute__((aligned(16))) u16   xlds[2][16][264];
  __shared__ __attribute__((aligned(16))) u16   Alds[16][520];
  __shared__ __attribute__((aligned(16))) float zlds[4][2][16][20];
  __shared__ __attribute__((aligned(16))) u16   hlds[4][16][8];

  const u16* wsrc = dir ? encB : encF;
  bf16x8 Breg[2][24];
#pragma unroll
  for (int n = 0; n < 2; ++n) {
    const int ntg = wgi * 8 + wave * 2 + n;
    const u16* fb = wsrc + (size_t)(ntg * 1536 + lane) * 8;
#pragma unroll
    for (int kt = 0; kt < 24; ++kt)
      Breg[n][kt] = pin_frag(fb + kt * 512);
  }
  wait_vm0();
  __builtin_amdgcn_sched_barrier(0);

  const float* bias = dir ? biasB : biasF;
  float bias_r[2];
  bias_r[0] = bias[(wgi * 8 + wave * 2 + 0) * 16 + l15];
  bias_r[1] = bias[(wgi * 8 + wave * 2 + 1) * 16 + l15];

  u16* myH = hbuf + (size_t)g * 16384;
  int* myFlags = flags + g * 16;
  const int* myPollFlag = &myFlags[tid >> 4];   // producer WG of this thread's chunks
  const int xr = tid >> 4, xc = tid & 15;       // x staging assignment
  const int cb = tid >> 2;                      // consumer unit-block 0..63
  const int cr0 = (tid & 3) * 4;                // consumer first row

  // prologue: stage x_{t(0)} into xlds[0]
  {
    const int t0 = dir ? 1023 : 0;
    const float* xp = x + ((size_t)(rowBase + xr) * 1024 + t0) * 256 + xc * 16;
    float4 f0 = *(const float4*)xp;
    float4 f1 = *(const float4*)(xp + 4);
    float4 f2 = *(const float4*)(xp + 8);
    float4 f3 = *(const float4*)(xp + 12);
    u16x8 a, b;
    a[0]=f2bf(f0.x); a[1]=f2bf(f0.y); a[2]=f2bf(f0.z); a[3]=f2bf(f0.w);
    a[4]=f2bf(f1.x); a[5]=f2bf(f1.y); a[6]=f2bf(f1.z); a[7]=f2bf(f1.w);
    b[0]=f2bf(f2.x); b[1]=f2bf(f2.y); b[2]=f2bf(f2.z); b[3]=f2bf(f2.w);
    b[4]=f2bf(f3.x); b[5]=f2bf(f3.y); b[6]=f2bf(f3.z); b[7]=f2bf(f3.w);
    *(u16x8*)&xlds[0][xr][xc * 16] = a;
    *(u16x8*)&xlds[0][xr][xc * 16 + 8] = b;
  }
  __syncthreads();

  float cc0 = 0.f, cc1 = 0.f;

  for (int s = 0; s < 1024; ++s) {
    // ---- P1: x-part MFMA from xlds[s&1] ----
    f32x4 acc0 = {bias_r[0], bias_r[0], bias_r[0], bias_r[0]};
    f32x4 acc1 = {bias_r[1], bias_r[1], bias_r[1], bias_r[1]};
#pragma unroll
    for (int kt = 0; kt < 8; ++kt) {
      bf16x8 av = *(const bf16x8*)&xlds[s & 1][l15][kt * 32 + lk * 8];
      acc0 = __builtin_amdgcn_mfma_f32_16x16x32_bf16(av, Breg[0][kt], acc0, 0, 0, 0);
      acc1 = __builtin_amdgcn_mfma_f32_16x16x32_bf16(av, Breg[1][kt], acc1, 0, 0, 0);
    }

    const int sn = (s + 1 < 1024) ? s + 1 : 1023;
    const int tn = dir ? (1023 - sn) : sn;
    const float* xp = x + ((size_t)(rowBase + xr) * 1024 + tn) * 256 + xc * 16;
    uint4 xq0, xq1, xq2, xq3;

    // ---- P2: flag poll -> h loads, THEN x loads, counted wait on h only ----
    if (s > 0) {
      poll_flag(myPollFlag, s);
      const u16* hs = myH + ((s - 1) & 1) * 8192 + cb * 128 + cr0 * 8;
      uint4 h0 = ld_coh_x4(hs);
      uint4 h1 = ld_coh_x4(hs + 8);
      uint4 h2 = ld_coh_x4(hs + 16);
      uint4 h3 = ld_coh_x4(hs + 24);
      xq0 = ld_x4(xp);           // next-step x: drains later, off the h path
      xq1 = ld_x4(xp + 4);
      xq2 = ld_x4(xp + 8);
      xq3 = ld_x4(xp + 12);
      wait_vm4();                // waits only the 4 h loads (oldest)
      __builtin_amdgcn_sched_barrier(0);
      *(uint4*)&Alds[cr0][cb * 8]     = h0;
      *(uint4*)&Alds[cr0 + 1][cb * 8] = h1;
      *(uint4*)&Alds[cr0 + 2][cb * 8] = h2;
      *(uint4*)&Alds[cr0 + 3][cb * 8] = h3;
      __syncthreads();
#pragma unroll
      for (int kt = 0; kt < 16; ++kt) {
        bf16x8 av = *(const bf16x8*)&Alds[l15][kt * 32 + lk * 8];
        acc0 = __builtin_amdgcn_mfma_f32_16x16x32_bf16(av, Breg[0][kt + 8], acc0, 0, 0, 0);
        acc1 = __builtin_amdgcn_mfma_f32_16x16x32_bf16(av, Breg[1][kt + 8], acc1, 0, 0, 0);
      }
    } else {
      xq0 = ld_x4(xp);
      xq1 = ld_x4(xp + 4);
      xq2 = ld_x4(xp + 8);
      xq3 = ld_x4(xp + 12);
    }

    // ---- P3: transpose gates (wave-local LDS), activations ----
#pragma unroll
    for (int r = 0; r < 4; ++r) {
      zlds[wave][0][lk * 4 + r][l15] = acc0[r];
      zlds[wave][1][lk * 4 + r][l15] = acc1[r];
    }
    asm volatile("s_waitcnt lgkmcnt(0)" ::: "memory");
    float4 g0 = *(const float4*)&zlds[wave][0][l15][lk * 4];
    float4 g1 = *(const float4*)&zlds[wave][1][l15][lk * 4];
    float hv0, hv1;
    { float iv = fsig(g0.x), fv = fsig(g0.y), gg = ftanhf(g0.z), ov = fsig(g0.w);
      cc0 = fv * cc0 + iv * gg;  hv0 = ov * ftanhf(cc0); }
    { float iv = fsig(g1.x), fv = fsig(g1.y), gg = ftanhf(g1.z), ov = fsig(g1.w);
      cc1 = fv * cc1 + iv * gg;  hv1 = ov * ftanhf(cc1); }

    // ---- P5: x loads done by now; convert + store to xlds[(s+1)&1] ----
    wait_vm0();
    __builtin_amdgcn_sched_barrier(0);
    {
      float4 f0 = __builtin_bit_cast(float4, xq0);
      float4 f1 = __builtin_bit_cast(float4, xq1);
      float4 f2 = __builtin_bit_cast(float4, xq2);
      float4 f3 = __builtin_bit_cast(float4, xq3);
      u16x8 a, b;
      a[0]=f2bf(f0.x); a[1]=f2bf(f0.y); a[2]=f2bf(f0.z); a[3]=f2bf(f0.w);
      a[4]=f2bf(f1.x); a[5]=f2bf(f1.y); a[6]=f2bf(f1.z); a[7]=f2bf(f1.w);
      b[0]=f2bf(f2.x); b[1]=f2bf(f2.y); b[2]=f2bf(f2.z); b[3]=f2bf(f2.w);
      b[4]=f2bf(f3.x); b[5]=f2bf(f3.y); b[6]=f2bf(f3.z); b[7]=f2bf(f3.w);
      *(u16x8*)&xlds[(s + 1) & 1][xr][xc * 16] = a;
      *(u16x8*)&xlds[(s + 1) & 1][xr][xc * 16 + 8] = b;
    }

    // ---- P4: wave-local gather + single 16B coherent store ----
    if (s < 1023) {
      hlds[wave][l15][lk]     = f2bf(hv0);
      hlds[wave][l15][lk + 4] = f2bf(hv1);
      asm volatile("s_waitcnt lgkmcnt(0)" ::: "memory");
      if (lane < 16) {
        const u32x4 c = *(const u32x4*)&hlds[wave][lane][0];
        u16* hw = myH + (s & 1) * 8192 + (wgi * 4 + wave) * 128 + lane * 8;
        st_coh_x4(hw, c);
      }
    } else {
      float* lp = latent + (size_t)(rowBase + l15) * 1024 + dir * 512 + wgi * 32 + wave * 8 + lk;
      lp[0] = hv0;
      lp[4] = hv1;
    }

    // ---- release: drain store, join, raise flag ----
    wait_vm0();
    __syncthreads();
    if (tid == 0 && s < 1023) flag_store(&myFlags[wgi], s + 1);
  }
}

// ---------------------------------------------------------------------------
// decoder: 8 groups x 16 rows, 16 WGs/group (128 WGs). xwd in regs; WG-level
// flags (16/group — r12 showed per-wave flags congest); Alds double-buffered
// => single barrier per step (the release join); fused Dense (wave0) after
// release, off the recurrent chain.
// ---------------------------------------------------------------------------
__global__ __launch_bounds__(256, 1) void dec_kernel(
    const float* __restrict__ latent,
    const u16* __restrict__ udF, const u16* __restrict__ wdF, const u16* __restrict__ woF,
    const float* __restrict__ biasD, const float* __restrict__ bo,
    float* __restrict__ out, u16* __restrict__ hbuf, int* __restrict__ flags)
{
  const int bid = blockIdx.x;      // 0..127
  const int g   = bid & 7;
  const int wgi = bid >> 3;        // 0..15
  const int rowBase = g * 16;
  const int tid = threadIdx.x;
  const int lane = tid & 63;
  const int wave = tid >> 6;
  const int l15 = lane & 15;
  const int lk  = lane >> 4;

  __shared__ __attribute__((aligned(16))) u16   Llds[16][1032];
  __shared__ __attribute__((aligned(16))) u16   Alds[2][16][520];
  __shared__ __attribute__((aligned(16))) float zlds[4][2][16][20];
  __shared__ __attribute__((aligned(16))) u16   hlds[4][16][8];

#pragma unroll
  for (int c8 = 0; c8 < 8; ++c8) {
    const int idx = tid + c8 * 256;
    const int rr = idx >> 7, cf = idx & 127;
    const float* lp = latent + (size_t)(rowBase + rr) * 1024 + cf * 8;
    float4 v0 = *(const float4*)lp;
    float4 v1 = *(const float4*)(lp + 4);
    u16x8 tv;
    tv[0]=f2bf(v0.x); tv[1]=f2bf(v0.y); tv[2]=f2bf(v0.z); tv[3]=f2bf(v0.w);
    tv[4]=f2bf(v1.x); tv[5]=f2bf(v1.y); tv[6]=f2bf(v1.z); tv[7]=f2bf(v1.w);
    *(u16x8*)&Llds[rr][cf * 8] = tv;
  }
  __syncthreads();

  f32x4 xwd[2];
#pragma unroll
  for (int n = 0; n < 2; ++n) {
    const int ntg = wgi * 8 + wave * 2 + n;
    const float br = biasD[ntg * 16 + l15];
    f32x4 xw = {br, br, br, br};
    const u16* wf = wdF + (size_t)(ntg * 2048 + lane) * 8;
#pragma unroll
    for (int kt = 0; kt < 32; ++kt) {
      bf16x8 b = *(const bf16x8*)(wf + kt * 512);
      bf16x8 a = *(const bf16x8*)&Llds[l15][kt * 32 + lk * 8];
      xw = __builtin_amdgcn_mfma_f32_16x16x32_bf16(a, b, xw, 0, 0, 0);
    }
    xwd[n] = xw;
  }

  bf16x8 Bu[2][16];
#pragma unroll
  for (int n = 0; n < 2; ++n) {
    const int ntg = wgi * 8 + wave * 2 + n;
    const u16* ub = udF + (size_t)(ntg * 1024 + lane) * 8;
#pragma unroll
    for (int kt = 0; kt < 16; ++kt)
      Bu[n][kt] = pin_frag(ub + kt * 512);
  }
  bf16x8 Bo[16];
  if (wave == 0) {
    const u16* ob = woF + (size_t)(wgi * 1024 + lane) * 8;
#pragma unroll
    for (int kt = 0; kt < 16; ++kt)
      Bo[kt] = pin_frag(ob + kt * 512);
  }
  wait_vm0();
  __builtin_amdgcn_sched_barrier(0);
  const float bo_r = bo[wgi * 16 + l15];

  u16* myH = hbuf + (size_t)g * 16384;
  int* myFlags = flags + g * 16;
  const int* myPollFlag = &myFlags[tid >> 4];
  const int cb = tid >> 2;
  const int cr0 = (tid & 3) * 4;

  float cc0 = 0.f, cc1 = 0.f;

  for (int t = 0; t < 1024; ++t) {
    f32x4 acc0 = xwd[0], acc1 = xwd[1];

    if (t > 0) {
      poll_flag(myPollFlag, t);
      const u16* hs = myH + ((t - 1) & 1) * 8192 + cb * 128 + cr0 * 8;
      uint4 h0 = ld_coh_x4(hs);
      uint4 h1 = ld_coh_x4(hs + 8);
      uint4 h2 = ld_coh_x4(hs + 16);
      uint4 h3 = ld_coh_x4(hs + 24);
      wait_vm0();
      __builtin_amdgcn_sched_barrier(0);
      *(uint4*)&Alds[t & 1][cr0][cb * 8]     = h0;
      *(uint4*)&Alds[t & 1][cr0 + 1][cb * 8] = h1;
      *(uint4*)&Alds[t & 1][cr0 + 2][cb * 8] = h2;
      *(uint4*)&Alds[t & 1][cr0 + 3][cb * 8] = h3;
      __syncthreads();
#pragma unroll
      for (int kt = 0; kt < 16; ++kt) {
        bf16x8 av = *(const bf16x8*)&Alds[t & 1][l15][kt * 32 + lk * 8];
        acc0 = __builtin_amdgcn_mfma_f32_16x16x32_bf16(av, Bu[0][kt], acc0, 0, 0, 0);
        acc1 = __builtin_amdgcn_mfma_f32_16x16x32_bf16(av, Bu[1][kt], acc1, 0, 0, 0);
      }
    }

#pragma unroll
    for (int r = 0; r < 4; ++r) {
      zlds[wave][0][lk * 4 + r][l15] = acc0[r];
      zlds[wave][1][lk * 4 + r][l15] = acc1[r];
    }
    asm volatile("s_waitcnt lgkmcnt(0)" ::: "memory");
    float4 g0 = *(const float4*)&zlds[wave][0][l15][lk * 4];
    float4 g1 = *(const float4*)&zlds[wave][1][l15][lk * 4];
    float hv0, hv1;
    { float iv = fsig(g0.x), fv = fsig(g0.y), gg = ftanhf(g0.z), ov = fsig(g0.w);
      cc0 = fv * cc0 + iv * gg;  hv0 = ov * ftanhf(cc0); }
    { float iv = fsig(g1.x), fv = fsig(g1.y), gg = ftanhf(g1.z), ov = fsig(g1.w);
      cc1 = fv * cc1 + iv * gg;  hv1 = ov * ftanhf(cc1); }

    // gather + single 16B coherent store + drain + join + flag
    {
      hlds[wave][l15][lk]     = f2bf(hv0);
      hlds[wave][l15][lk + 4] = f2bf(hv1);
      asm volatile("s_waitcnt lgkmcnt(0)" ::: "memory");
      if (lane < 16) {
        const u32x4 c = *(const u32x4*)&hlds[wave][lane][0];
        u16* hw = myH + (t & 1) * 8192 + (wgi * 4 + wave) * 128 + lane * 8;
        st_coh_x4(hw, c);
      }
      wait_vm0();
      __syncthreads();           // the single per-step join
      if (tid == 0) flag_store(&myFlags[wgi], t + 1);
    }

    // fused Dense for out[:, t-1, :] — after release, off the chain.
    // Alds double-buffer: next step's staging targets buffer (t+1)&1, so no
    // loop-end barrier is needed while wave0 still reads buffer t&1 here.
    if (t > 0 && wave == 0) {
      f32x4 od = {bo_r, bo_r, bo_r, bo_r};
#pragma unroll
      for (int kt = 0; kt < 16; ++kt) {
        bf16x8 a = *(const bf16x8*)&Alds[t & 1][l15][kt * 32 + lk * 8];
        od = __builtin_amdgcn_mfma_f32_16x16x32_bf16(a, Bo[kt], od, 0, 0, 0);
      }
#pragma unroll
      for (int r = 0; r < 4; ++r)
        out[((size_t)(rowBase + lk * 4 + r) * 1024 + (t - 1)) * 256 + wgi * 16 + l15] = od[r];
    }
    // no loop-end barrier: Alds double-buffered; zlds/hlds are wave-local
  }

  // out[:, 1023, :] — stage h_1023 into Alds[0] (dense(1023) reads Alds[1])
  poll_flag(myPollFlag, 1024);
  {
    const u16* hs = myH + 8192 + cb * 128 + cr0 * 8;   // slot 1 = h_1023
    uint4 h0 = ld_coh_x4(hs);
    uint4 h1 = ld_coh_x4(hs + 8);
    uint4 h2 = ld_coh_x4(hs + 16);
    uint4 h3 = ld_coh_x4(hs + 24);
    wait_vm0();
    __builtin_amdgcn_sched_barrier(0);
    *(uint4*)&Alds[0][cr0][cb * 8]     = h0;
    *(uint4*)&Alds[0][cr0 + 1][cb * 8] = h1;
    *(uint4*)&Alds[0][cr0 + 2][cb * 8] = h2;
    *(uint4*)&Alds[0][cr0 + 3][cb * 8] = h3;
    __syncthreads();
    if (wave == 0) {
      f32x4 od = {bo_r, bo_r, bo_r, bo_r};
#pragma unroll
      for (int kt = 0; kt < 16; ++kt) {
        bf16x8 a = *(const bf16x8*)&Alds[0][l15][kt * 32 + lk * 8];
        od = __builtin_amdgcn_mfma_f32_16x16x32_bf16(a, Bo[kt], od, 0, 0, 0);
      }
#pragma unroll
      for (int r = 0; r < 4; ++r)
        out[((size_t)(rowBase + lk * 4 + r) * 1024 + 1023) * 256 + wgi * 16 + l15] = od[r];
    }
  }
}

// ---------------------------------------------------------------------------
extern "C" void kernel_launch(void* const* d_in, const int* in_sizes, int n_in,
                              void* d_out, int out_size, void* d_ws, size_t ws_size,
                              hipStream_t stream)
{
  const float* x  = (const float*)d_in[0];
  const float* Wf = (const float*)d_in[1];
  const float* Uf = (const float*)d_in[2];
  const float* bf = (const float*)d_in[3];
  const float* Wb = (const float*)d_in[4];
  const float* Ub = (const float*)d_in[5];
  const float* bb = (const float*)d_in[6];
  const float* Wd = (const float*)d_in[7];
  const float* Ud = (const float*)d_in[8];
  const float* bd = (const float*)d_in[9];
  const float* Wo = (const float*)d_in[10];
  const float* bo = (const float*)d_in[11];

  if (ws_size < 14182400) return;

  char* ws = (char*)d_ws;
  u16*  encF   = (u16*)(ws + 0);
  u16*  encB   = (u16*)(ws + 3145728);
  u16*  udF    = (u16*)(ws + 6291456);
  u16*  wdF    = (u16*)(ws + 8388608);
  u16*  woF    = (u16*)(ws + 12582912);
  float* biasF = (float*)(ws + 12845056);
  float* biasB = (float*)(ws + 12853248);
  float* biasD = (float*)(ws + 12861440);
  float* latent= (float*)(ws + 12869632);
  u16*  hbufE  = (u16*)(ws + 13393920);   // 16 groups * 16384 u16 = 512KB
  u16*  hbufD  = (u16*)(ws + 13918208);   // 8 groups * 16384 u16 = 256KB
  int*  flagsE = (int*)(ws + 14180352);   // 256 ints
  int*  flagsD = (int*)(ws + 14181376);   // 128 ints (prep zeroes 512-int range)

  prep_kernel<<<256, 256, 0, stream>>>(Wf, Uf, bf, Wb, Ub, bb, Wd, Ud, bd, Wo,
                                       encF, encB, udF, wdF, woF,
                                       biasF, biasB, biasD, flagsE);
  enc_kernel<<<256, 256, 0, stream>>>(x, encF, encB, biasF, biasB, latent, hbufE, flagsE);
  dec_kernel<<<128, 256, 0, stream>>>(latent, udF, wdF, woF, biasD, bo,
                                      (float*)d_out, hbufD, flagsD);
}

// Round 14
// 5560.389 us; speedup vs baseline: 1.1783x; 1.0665x over previous
//
#include <hip/hip_runtime.h>
#include <stdint.h>

typedef unsigned short u16;
typedef short bf16x8 __attribute__((ext_vector_type(8)));
typedef float f32x4  __attribute__((ext_vector_type(4)));
typedef unsigned short u16x8 __attribute__((ext_vector_type(8)));
typedef unsigned int   u32x4 __attribute__((ext_vector_type(4)));

__device__ __forceinline__ u16 f2bf(float f) {
  uint32_t u = __float_as_uint(f);
  return (u16)((u + 0x7FFFu + ((u >> 16) & 1u)) >> 16);
}
__device__ __forceinline__ float fsig(float x) {
  x = fminf(fmaxf(x, -30.f), 30.f);
  return __builtin_amdgcn_rcpf(1.f + __builtin_amdgcn_exp2f(-1.44269504088896f * x));
}
__device__ __forceinline__ float ftanhf(float x) {
  x = fminf(fmaxf(x, -10.f), 10.f);
  float e = __builtin_amdgcn_exp2f(2.88539008177793f * x);
  return (e - 1.f) * __builtin_amdgcn_rcpf(e + 1.f);
}

// Coherent (cross-XCD) ops: sc0 sc1 => bypass L1/L2, serialize at MALL.
// r11: sc0-only exchange broken. r12: per-wave flags congest. r14: 16-poller
// + barrier release (240 fewer coherent pollers per WG).
__device__ __forceinline__ int flag_load(const int* p) {
  int v;
  asm volatile("global_load_dword %0, %1, off sc0 sc1\n\ts_waitcnt vmcnt(0)"
               : "=v"(v) : "v"(p) : "memory");
  return v;
}
__device__ __forceinline__ void flag_store(int* p, int v) {
  asm volatile("global_store_dword %0, %1, off sc0 sc1" :: "v"(p), "v"(v) : "memory");
}
__device__ __forceinline__ uint4 ld_coh_x4(const u16* p) {   // issue only
  uint4 v;
  asm volatile("global_load_dwordx4 %0, %1, off sc0 sc1" : "=v"(v) : "v"(p) : "memory");
  return v;
}
// 16B coherent store; u32x4 ext-vector input (struct inputs don't lower to "v")
__device__ __forceinline__ void st_coh_x4(u16* p, u32x4 v) {
  asm volatile("global_store_dwordx4 %0, %1, off sc0 sc1" :: "v"(p), "v"(v) : "memory");
}
// plain cached 16B load, issue-only (x staging overlaps the poll)
__device__ __forceinline__ uint4 ld_x4(const float* p) {
  uint4 v;
  asm volatile("global_load_dwordx4 %0, %1, off" : "=v"(v) : "v"(p) : "memory");
  return v;
}
__device__ __forceinline__ void wait_vm0() {
  asm volatile("s_waitcnt vmcnt(0)" ::: "memory");
}
// Weight-fragment load via volatile asm: result must stay resident (VGPR/AGPR).
__device__ __forceinline__ bf16x8 pin_frag(const u16* p) {
  uint4 v;
  asm volatile("global_load_dwordx4 %0, %1, off" : "=v"(v) : "v"(p));
  return __builtin_bit_cast(bf16x8, v);
}
// Paced poll (s_sleep(1) between iterations; unpaced spinning congests MALL).
__device__ __forceinline__ void poll_flag(const int* fp, int target) {
  int spins = 0;
  while (flag_load(fp) < target) {
    __builtin_amdgcn_s_sleep(1);
    if (++spins > 200000) break;   // bounded: broken sync -> wrong answer, not hang
  }
}

// ---------------------------------------------------------------------------
// prep: f32 weights -> bf16 MFMA fragment layout, gate-permuted columns;
// zeroes the 512 flag ints. n' = 4*unit + gate => original col = gate*512+unit.
// ---------------------------------------------------------------------------
__global__ void prep_kernel(const float* __restrict__ Wf, const float* __restrict__ Uf, const float* __restrict__ bf,
                            const float* __restrict__ Wb, const float* __restrict__ Ub, const float* __restrict__ bb,
                            const float* __restrict__ Wd, const float* __restrict__ Ud, const float* __restrict__ bd,
                            const float* __restrict__ Wo,
                            u16* __restrict__ encF, u16* __restrict__ encB,
                            u16* __restrict__ udF, u16* __restrict__ wdF, u16* __restrict__ woF,
                            float* __restrict__ biasF, float* __restrict__ biasB, float* __restrict__ biasD,
                            int* __restrict__ flagsAll)
{
  constexpr int NC_ENC = 128 * 24 * 64;
  constexpr int NC_UD  = 128 * 16 * 64;
  constexpr int NC_WD  = 128 * 32 * 64;
  constexpr int NC_WO  = 16 * 16 * 64;
  constexpr int B1 = 2 * NC_ENC;
  constexpr int B2 = B1 + NC_UD;
  constexpr int B3 = B2 + NC_WD;
  constexpr int B4 = B3 + NC_WO;
  constexpr int B5 = B4 + 768;
  constexpr int TOTAL = B5 + 64;

  for (int idx = blockIdx.x * 256 + threadIdx.x; idx < TOTAL; idx += gridDim.x * 256) {
    if (idx < B1) {
      int d = idx / NC_ENC;
      int r = idx - d * NC_ENC;
      int ntg = r / 1536;
      int rem = r - ntg * 1536;
      int kt = rem >> 6, lane = rem & 63;
      int np = ntg * 16 + (lane & 15);
      int col = (np & 3) * 512 + (np >> 2);
      int kb = kt * 32 + (lane >> 4) * 8;
      const float* W = d ? Wb : Wf;
      const float* U = d ? Ub : Uf;
      u16* dst = (d ? encB : encF) + (size_t)r * 8;
      if (kb < 256) {
        const float* s = W + (size_t)kb * 2048 + col;
#pragma unroll
        for (int e = 0; e < 8; ++e) dst[e] = f2bf(s[(size_t)e * 2048]);
      } else {
        const float* s = U + (size_t)(kb - 256) * 2048 + col;
#pragma unroll
        for (int e = 0; e < 8; ++e) dst[e] = f2bf(s[(size_t)e * 2048]);
      }
    } else if (idx < B2) {
      int r = idx - B1;
      int ntg = r / 1024;
      int rem = r - ntg * 1024;
      int kt = rem >> 6, lane = rem & 63;
      int np = ntg * 16 + (lane & 15);
      int col = (np & 3) * 512 + (np >> 2);
      int kb = kt * 32 + (lane >> 4) * 8;
      const float* s = Ud + (size_t)kb * 2048 + col;
      u16* dst = udF + (size_t)r * 8;
#pragma unroll
      for (int e = 0; e < 8; ++e) dst[e] = f2bf(s[(size_t)e * 2048]);
    } else if (idx < B3) {
      int r = idx - B2;
      int ntg = r / 2048;
      int rem = r - ntg * 2048;
      int kt = rem >> 6, lane = rem & 63;
      int np = ntg * 16 + (lane & 15);
      int col = (np & 3) * 512 + (np >> 2);
      int kb = kt * 32 + (lane >> 4) * 8;
      const float* s = Wd + (size_t)kb * 2048 + col;
      u16* dst = wdF + (size_t)r * 8;
#pragma unroll
      for (int e = 0; e < 8; ++e) dst[e] = f2bf(s[(size_t)e * 2048]);
    } else if (idx < B4) {
      int r = idx - B3;
      int nt = r / 1024;
      int rem = r - nt * 1024;
      int kt = rem >> 6, lane = rem & 63;
      int col = nt * 16 + (lane & 15);
      int kb = kt * 32 + (lane >> 4) * 8;
      const float* s = Wo + (size_t)kb * 256 + col;
      u16* dst = woF + (size_t)r * 8;
#pragma unroll
      for (int e = 0; e < 8; ++e) dst[e] = f2bf(s[(size_t)e * 256]);
    } else if (idx < B5) {
      int r = idx - B4;
      int which = r >> 8;
      int j0 = (r & 255) * 8;
      const float* src = (which == 0) ? bf : (which == 1) ? bb : bd;
      float* dstb = (which == 0) ? biasF : (which == 1) ? biasB : biasD;
#pragma unroll
      for (int e = 0; e < 8; ++e) {
        int np = j0 + e;
        dstb[np] = src[(np & 3) * 512 + (np >> 2)];
      }
    } else {
      int r = idx - B5;
#pragma unroll
      for (int e = 0; e < 8; ++e) flagsAll[r * 8 + e] = 0;
    }
  }
}

// ---------------------------------------------------------------------------
// h exchange layout (per group, per slot of 8192 u16):
//   chunk(b,row) = 8 u16 (units b*8..b*8+7, batch row) at u16 offset b*128+row*8.
//   Producer: wave w of WG wgi owns b = wgi*4+w -> 16 chunks, 256B contiguous,
//   one dwordx4 store per lane<16.
//   Consumer thread tid: b = tid>>2, rows (tid&3)*4+k (k=0..3) at
//   hs, hs+8, hs+16, hs+24. Poll: threads tid<16 each poll producer-WG tid's
//   flag; one barrier releases the WG (16 coherent pollers, not 256).
// ---------------------------------------------------------------------------

// encoder: 16 groups (dir=g>>3, rows (g&7)*16..+15), 16 WGs/group, 1 WG/CU.
__global__ __launch_bounds__(256, 1) void enc_kernel(
    const float* __restrict__ x,
    const u16* __restrict__ encF, const u16* __restrict__ encB,
    const float* __restrict__ biasF, const float* __restrict__ biasB,
    float* __restrict__ latent, u16* __restrict__ hbuf, int* __restrict__ flags)
{
  const int bid = blockIdx.x;
  const int g   = bid & 15;
  const int wgi = bid >> 4;
  const int dir = g >> 3;
  const int rowBase = (g & 7) * 16;
  const int tid = threadIdx.x;
  const int lane = tid & 63;
  const int wave = tid >> 6;
  const int l15 = lane & 15;
  const int lk  = lane >> 4;

  __shared__ __attribute__((aligned(16))) u16   xlds[2][16][264];
  __shared__ __attribute__((aligned(16))) u16   Alds[16][520];
  __shared__ __attribute__((aligned(16))) float zlds[4][2][16][20];
  __shared__ __attribute__((aligned(16))) u16   hlds[4][16][8];

  const u16* wsrc = dir ? encB : encF;
  bf16x8 Breg[2][24];
#pragma unroll
  for (int n = 0; n < 2; ++n) {
    const int ntg = wgi * 8 + wave * 2 + n;
    const u16* fb = wsrc + (size_t)(ntg * 1536 + lane) * 8;
#pragma unroll
    for (int kt = 0; kt < 24; ++kt)
      Breg[n][kt] = pin_frag(fb + kt * 512);
  }
  wait_vm0();
  __builtin_amdgcn_sched_barrier(0);

  const float* bias = dir ? biasB : biasF;
  float bias_r[2];
  bias_r[0] = bias[(wgi * 8 + wave * 2 + 0) * 16 + l15];
  bias_r[1] = bias[(wgi * 8 + wave * 2 + 1) * 16 + l15];

  u16* myH = hbuf + (size_t)g * 16384;
  int* myFlags = flags + g * 16;
  const int xr = tid >> 4, xc = tid & 15;       // x staging assignment
  const int cb = tid >> 2;                      // consumer unit-block 0..63
  const int cr0 = (tid & 3) * 4;                // consumer first row

  // prologue: stage x_{t(0)} into xlds[0]
  {
    const int t0 = dir ? 1023 : 0;
    const float* xp = x + ((size_t)(rowBase + xr) * 1024 + t0) * 256 + xc * 16;
    float4 f0 = *(const float4*)xp;
    float4 f1 = *(const float4*)(xp + 4);
    float4 f2 = *(const float4*)(xp + 8);
    float4 f3 = *(const float4*)(xp + 12);
    u16x8 a, b;
    a[0]=f2bf(f0.x); a[1]=f2bf(f0.y); a[2]=f2bf(f0.z); a[3]=f2bf(f0.w);
    a[4]=f2bf(f1.x); a[5]=f2bf(f1.y); a[6]=f2bf(f1.z); a[7]=f2bf(f1.w);
    b[0]=f2bf(f2.x); b[1]=f2bf(f2.y); b[2]=f2bf(f2.z); b[3]=f2bf(f2.w);
    b[4]=f2bf(f3.x); b[5]=f2bf(f3.y); b[6]=f2bf(f3.z); b[7]=f2bf(f3.w);
    *(u16x8*)&xlds[0][xr][xc * 16] = a;
    *(u16x8*)&xlds[0][xr][xc * 16 + 8] = b;
  }
  __syncthreads();

  float cc0 = 0.f, cc1 = 0.f;

  for (int s = 0; s < 1024; ++s) {
    // ---- P1: x-part MFMA from xlds[s&1] ----
    f32x4 acc0 = {bias_r[0], bias_r[0], bias_r[0], bias_r[0]};
    f32x4 acc1 = {bias_r[1], bias_r[1], bias_r[1], bias_r[1]};
#pragma unroll
    for (int kt = 0; kt < 8; ++kt) {
      bf16x8 av = *(const bf16x8*)&xlds[s & 1][l15][kt * 32 + lk * 8];
      acc0 = __builtin_amdgcn_mfma_f32_16x16x32_bf16(av, Breg[0][kt], acc0, 0, 0, 0);
      acc1 = __builtin_amdgcn_mfma_f32_16x16x32_bf16(av, Breg[1][kt], acc1, 0, 0, 0);
    }

    // ---- P0: issue x loads for next step (overlap the poll) ----
    const int sn = (s + 1 < 1024) ? s + 1 : 1023;
    const int tn = dir ? (1023 - sn) : sn;
    const float* xp = x + ((size_t)(rowBase + xr) * 1024 + tn) * 256 + xc * 16;
    uint4 xq0 = ld_x4(xp);
    uint4 xq1 = ld_x4(xp + 4);
    uint4 xq2 = ld_x4(xp + 8);
    uint4 xq3 = ld_x4(xp + 12);

    // ---- P2: 16-poller flag wait + barrier release -> h loads -> MFMA ----
    if (s > 0) {
      if (tid < 16) poll_flag(&myFlags[tid], s);
      __syncthreads();           // releases 240 non-polling threads
      const u16* hs = myH + ((s - 1) & 1) * 8192 + cb * 128 + cr0 * 8;
      uint4 h0 = ld_coh_x4(hs);
      uint4 h1 = ld_coh_x4(hs + 8);
      uint4 h2 = ld_coh_x4(hs + 16);
      uint4 h3 = ld_coh_x4(hs + 24);
      wait_vm0();                // h loads (x loads returned during the poll)
      __builtin_amdgcn_sched_barrier(0);
      *(uint4*)&Alds[cr0][cb * 8]     = h0;
      *(uint4*)&Alds[cr0 + 1][cb * 8] = h1;
      *(uint4*)&Alds[cr0 + 2][cb * 8] = h2;
      *(uint4*)&Alds[cr0 + 3][cb * 8] = h3;
      __syncthreads();
#pragma unroll
      for (int kt = 0; kt < 16; ++kt) {
        bf16x8 av = *(const bf16x8*)&Alds[l15][kt * 32 + lk * 8];
        acc0 = __builtin_amdgcn_mfma_f32_16x16x32_bf16(av, Breg[0][kt + 8], acc0, 0, 0, 0);
        acc1 = __builtin_amdgcn_mfma_f32_16x16x32_bf16(av, Breg[1][kt + 8], acc1, 0, 0, 0);
      }
    } else {
      wait_vm0();                // drain x loads
      __builtin_amdgcn_sched_barrier(0);
    }

    // ---- P3: transpose gates (wave-local LDS), activations ----
#pragma unroll
    for (int r = 0; r < 4; ++r) {
      zlds[wave][0][lk * 4 + r][l15] = acc0[r];
      zlds[wave][1][lk * 4 + r][l15] = acc1[r];
    }
    asm volatile("s_waitcnt lgkmcnt(0)" ::: "memory");
    float4 g0 = *(const float4*)&zlds[wave][0][l15][lk * 4];
    float4 g1 = *(const float4*)&zlds[wave][1][l15][lk * 4];
    float hv0, hv1;
    { float iv = fsig(g0.x), fv = fsig(g0.y), gg = ftanhf(g0.z), ov = fsig(g0.w);
      cc0 = fv * cc0 + iv * gg;  hv0 = ov * ftanhf(cc0); }
    { float iv = fsig(g1.x), fv = fsig(g1.y), gg = ftanhf(g1.z), ov = fsig(g1.w);
      cc1 = fv * cc1 + iv * gg;  hv1 = ov * ftanhf(cc1); }

    // ---- P5: convert + store x for next step (x regs drained above) ----
    {
      float4 f0 = __builtin_bit_cast(float4, xq0);
      float4 f1 = __builtin_bit_cast(float4, xq1);
      float4 f2 = __builtin_bit_cast(float4, xq2);
      float4 f3 = __builtin_bit_cast(float4, xq3);
      u16x8 a, b;
      a[0]=f2bf(f0.x); a[1]=f2bf(f0.y); a[2]=f2bf(f0.z); a[3]=f2bf(f0.w);
      a[4]=f2bf(f1.x); a[5]=f2bf(f1.y); a[6]=f2bf(f1.z); a[7]=f2bf(f1.w);
      b[0]=f2bf(f2.x); b[1]=f2bf(f2.y); b[2]=f2bf(f2.z); b[3]=f2bf(f2.w);
      b[4]=f2bf(f3.x); b[5]=f2bf(f3.y); b[6]=f2bf(f3.z); b[7]=f2bf(f3.w);
      *(u16x8*)&xlds[(s + 1) & 1][xr][xc * 16] = a;
      *(u16x8*)&xlds[(s + 1) & 1][xr][xc * 16 + 8] = b;
    }

    // ---- P4: wave-local gather + single 16B coherent store ----
    if (s < 1023) {
      hlds[wave][l15][lk]     = f2bf(hv0);
      hlds[wave][l15][lk + 4] = f2bf(hv1);
      asm volatile("s_waitcnt lgkmcnt(0)" ::: "memory");
      if (lane < 16) {
        const u32x4 c = *(const u32x4*)&hlds[wave][lane][0];
        u16* hw = myH + (s & 1) * 8192 + (wgi * 4 + wave) * 128 + lane * 8;
        st_coh_x4(hw, c);
      }
    } else {
      float* lp = latent + (size_t)(rowBase + l15) * 1024 + dir * 512 + wgi * 32 + wave * 8 + lk;
      lp[0] = hv0;
      lp[4] = hv1;
    }

    // ---- release: drain store, join, raise flag ----
    wait_vm0();
    __syncthreads();
    if (tid == 0 && s < 1023) flag_store(&myFlags[wgi], s + 1);
  }
}

// ---------------------------------------------------------------------------
// decoder: 8 groups x 16 rows, 16 WGs/group (128 WGs). xwd in regs; WG-level
// flags; 16-poller + barrier release; Alds double-buffered (no loop-end
// barrier); fused Dense (wave0) after release, off the recurrent chain.
// ---------------------------------------------------------------------------
__global__ __launch_bounds__(256, 1) void dec_kernel(
    const float* __restrict__ latent,
    const u16* __restrict__ udF, const u16* __restrict__ wdF, const u16* __restrict__ woF,
    const float* __restrict__ biasD, const float* __restrict__ bo,
    float* __restrict__ out, u16* __restrict__ hbuf, int* __restrict__ flags)
{
  const int bid = blockIdx.x;      // 0..127
  const int g   = bid & 7;
  const int wgi = bid >> 3;        // 0..15
  const int rowBase = g * 16;
  const int tid = threadIdx.x;
  const int lane = tid & 63;
  const int wave = tid >> 6;
  const int l15 = lane & 15;
  const int lk  = lane >> 4;

  __shared__ __attribute__((aligned(16))) u16   Llds[16][1032];
  __shared__ __attribute__((aligned(16))) u16   Alds[2][16][520];
  __shared__ __attribute__((aligned(16))) float zlds[4][2][16][20];
  __shared__ __attribute__((aligned(16))) u16   hlds[4][16][8];

#pragma unroll
  for (int c8 = 0; c8 < 8; ++c8) {
    const int idx = tid + c8 * 256;
    const int rr = idx >> 7, cf = idx & 127;
    const float* lp = latent + (size_t)(rowBase + rr) * 1024 + cf * 8;
    float4 v0 = *(const float4*)lp;
    float4 v1 = *(const float4*)(lp + 4);
    u16x8 tv;
    tv[0]=f2bf(v0.x); tv[1]=f2bf(v0.y); tv[2]=f2bf(v0.z); tv[3]=f2bf(v0.w);
    tv[4]=f2bf(v1.x); tv[5]=f2bf(v1.y); tv[6]=f2bf(v1.z); tv[7]=f2bf(v1.w);
    *(u16x8*)&Llds[rr][cf * 8] = tv;
  }
  __syncthreads();

  f32x4 xwd[2];
#pragma unroll
  for (int n = 0; n < 2; ++n) {
    const int ntg = wgi * 8 + wave * 2 + n;
    const float br = biasD[ntg * 16 + l15];
    f32x4 xw = {br, br, br, br};
    const u16* wf = wdF + (size_t)(ntg * 2048 + lane) * 8;
#pragma unroll
    for (int kt = 0; kt < 32; ++kt) {
      bf16x8 b = *(const bf16x8*)(wf + kt * 512);
      bf16x8 a = *(const bf16x8*)&Llds[l15][kt * 32 + lk * 8];
      xw = __builtin_amdgcn_mfma_f32_16x16x32_bf16(a, b, xw, 0, 0, 0);
    }
    xwd[n] = xw;
  }

  bf16x8 Bu[2][16];
#pragma unroll
  for (int n = 0; n < 2; ++n) {
    const int ntg = wgi * 8 + wave * 2 + n;
    const u16* ub = udF + (size_t)(ntg * 1024 + lane) * 8;
#pragma unroll
    for (int kt = 0; kt < 16; ++kt)
      Bu[n][kt] = pin_frag(ub + kt * 512);
  }
  bf16x8 Bo[16];
  if (wave == 0) {
    const u16* ob = woF + (size_t)(wgi * 1024 + lane) * 8;
#pragma unroll
    for (int kt = 0; kt < 16; ++kt)
      Bo[kt] = pin_frag(ob + kt * 512);
  }
  wait_vm0();
  __builtin_amdgcn_sched_barrier(0);
  const float bo_r = bo[wgi * 16 + l15];

  u16* myH = hbuf + (size_t)g * 16384;
  int* myFlags = flags + g * 16;
  const int cb = tid >> 2;
  const int cr0 = (tid & 3) * 4;

  float cc0 = 0.f, cc1 = 0.f;

  for (int t = 0; t < 1024; ++t) {
    f32x4 acc0 = xwd[0], acc1 = xwd[1];

    if (t > 0) {
      if (tid < 16) poll_flag(&myFlags[tid], t);
      __syncthreads();           // releases 240 non-polling threads
      const u16* hs = myH + ((t - 1) & 1) * 8192 + cb * 128 + cr0 * 8;
      uint4 h0 = ld_coh_x4(hs);
      uint4 h1 = ld_coh_x4(hs + 8);
      uint4 h2 = ld_coh_x4(hs + 16);
      uint4 h3 = ld_coh_x4(hs + 24);
      wait_vm0();                // also drains last step's dense out-stores
      __builtin_amdgcn_sched_barrier(0);
      *(uint4*)&Alds[t & 1][cr0][cb * 8]     = h0;
      *(uint4*)&Alds[t & 1][cr0 + 1][cb * 8] = h1;
      *(uint4*)&Alds[t & 1][cr0 + 2][cb * 8] = h2;
      *(uint4*)&Alds[t & 1][cr0 + 3][cb * 8] = h3;
      __syncthreads();
#pragma unroll
      for (int kt = 0; kt < 16; ++kt) {
        bf16x8 av = *(const bf16x8*)&Alds[t & 1][l15][kt * 32 + lk * 8];
        acc0 = __builtin_amdgcn_mfma_f32_16x16x32_bf16(av, Bu[0][kt], acc0, 0, 0, 0);
        acc1 = __builtin_amdgcn_mfma_f32_16x16x32_bf16(av, Bu[1][kt], acc1, 0, 0, 0);
      }
    }

#pragma unroll
    for (int r = 0; r < 4; ++r) {
      zlds[wave][0][lk * 4 + r][l15] = acc0[r];
      zlds[wave][1][lk * 4 + r][l15] = acc1[r];
    }
    asm volatile("s_waitcnt lgkmcnt(0)" ::: "memory");
    float4 g0 = *(const float4*)&zlds[wave][0][l15][lk * 4];
    float4 g1 = *(const float4*)&zlds[wave][1][l15][lk * 4];
    float hv0, hv1;
    { float iv = fsig(g0.x), fv = fsig(g0.y), gg = ftanhf(g0.z), ov = fsig(g0.w);
      cc0 = fv * cc0 + iv * gg;  hv0 = ov * ftanhf(cc0); }
    { float iv = fsig(g1.x), fv = fsig(g1.y), gg = ftanhf(g1.z), ov = fsig(g1.w);
      cc1 = fv * cc1 + iv * gg;  hv1 = ov * ftanhf(cc1); }

    // gather + single 16B coherent store + drain + join + flag
    {
      hlds[wave][l15][lk]     = f2bf(hv0);
      hlds[wave][l15][lk + 4] = f2bf(hv1);
      asm volatile("s_waitcnt lgkmcnt(0)" ::: "memory");
      if (lane < 16) {
        const u32x4 c = *(const u32x4*)&hlds[wave][lane][0];
        u16* hw = myH + (t & 1) * 8192 + (wgi * 4 + wave) * 128 + lane * 8;
        st_coh_x4(hw, c);
      }
      wait_vm0();
      __syncthreads();           // the per-step join
      if (tid == 0) flag_store(&myFlags[wgi], t + 1);
    }

    // fused Dense for out[:, t-1, :] — after release, off the chain.
    if (t > 0 && wave == 0) {
      f32x4 od = {bo_r, bo_r, bo_r, bo_r};
#pragma unroll
      for (int kt = 0; kt < 16; ++kt) {
        bf16x8 a = *(const bf16x8*)&Alds[t & 1][l15][kt * 32 + lk * 8];
        od = __builtin_amdgcn_mfma_f32_16x16x32_bf16(a, Bo[kt], od, 0, 0, 0);
      }
#pragma unroll
      for (int r = 0; r < 4; ++r)
        out[((size_t)(rowBase + lk * 4 + r) * 1024 + (t - 1)) * 256 + wgi * 16 + l15] = od[r];
    }
    // no loop-end barrier: Alds double-buffered; zlds/hlds are wave-local
  }

  // out[:, 1023, :] — stage h_1023 into Alds[0] (dense(1023) reads Alds[1])
  if (tid < 16) poll_flag(&myFlags[tid], 1024);
  __syncthreads();
  {
    const u16* hs = myH + 8192 + cb * 128 + cr0 * 8;   // slot 1 = h_1023
    uint4 h0 = ld_coh_x4(hs);
    uint4 h1 = ld_coh_x4(hs + 8);
    uint4 h2 = ld_coh_x4(hs + 16);
    uint4 h3 = ld_coh_x4(hs + 24);
    wait_vm0();
    __builtin_amdgcn_sched_barrier(0);
    *(uint4*)&Alds[0][cr0][cb * 8]     = h0;
    *(uint4*)&Alds[0][cr0 + 1][cb * 8] = h1;
    *(uint4*)&Alds[0][cr0 + 2][cb * 8] = h2;
    *(uint4*)&Alds[0][cr0 + 3][cb * 8] = h3;
    __syncthreads();
    if (wave == 0) {
      f32x4 od = {bo_r, bo_r, bo_r, bo_r};
#pragma unroll
      for (int kt = 0; kt < 16; ++kt) {
        bf16x8 a = *(const bf16x8*)&Alds[0][l15][kt * 32 + lk * 8];
        od = __builtin_amdgcn_mfma_f32_16x16x32_bf16(a, Bo[kt], od, 0, 0, 0);
      }
#pragma unroll
      for (int r = 0; r < 4; ++r)
        out[((size_t)(rowBase + lk * 4 + r) * 1024 + 1023) * 256 + wgi * 16 + l15] = od[r];
    }
  }
}

// ---------------------------------------------------------------------------
extern "C" void kernel_launch(void* const* d_in, const int* in_sizes, int n_in,
                              void* d_out, int out_size, void* d_ws, size_t ws_size,
                              hipStream_t stream)
{
  const float* x  = (const float*)d_in[0];
  const float* Wf = (const float*)d_in[1];
  const float* Uf = (const float*)d_in[2];
  const float* bf = (const float*)d_in[3];
  const float* Wb = (const float*)d_in[4];
  const float* Ub = (const float*)d_in[5];
  const float* bb = (const float*)d_in[6];
  const float* Wd = (const float*)d_in[7];
  const float* Ud = (const float*)d_in[8];
  const float* bd = (const float*)d_in[9];
  const float* Wo = (const float*)d_in[10];
  const float* bo = (const float*)d_in[11];

  if (ws_size < 14182400) return;

  char* ws = (char*)d_ws;
  u16*  encF   = (u16*)(ws + 0);
  u16*  encB   = (u16*)(ws + 3145728);
  u16*  udF    = (u16*)(ws + 6291456);
  u16*  wdF    = (u16*)(ws + 8388608);
  u16*  woF    = (u16*)(ws + 12582912);
  float* biasF = (float*)(ws + 12845056);
  float* biasB = (float*)(ws + 12853248);
  float* biasD = (float*)(ws + 12861440);
  float* latent= (float*)(ws + 12869632);
  u16*  hbufE  = (u16*)(ws + 13393920);   // 16 groups * 16384 u16 = 512KB
  u16*  hbufD  = (u16*)(ws + 13918208);   // 8 groups * 16384 u16 = 256KB
  int*  flagsE = (int*)(ws + 14180352);   // 256 ints
  int*  flagsD = (int*)(ws + 14181376);   // 128 ints (prep zeroes 512-int range)

  prep_kernel<<<256, 256, 0, stream>>>(Wf, Uf, bf, Wb, Ub, bb, Wd, Ud, bd, Wo,
                                       encF, encB, udF, wdF, woF,
                                       biasF, biasB, biasD, flagsE);
  enc_kernel<<<256, 256, 0, stream>>>(x, encF, encB, biasF, biasB, latent, hbufE, flagsE);
  dec_kernel<<<128, 256, 0, stream>>>(latent, udF, wdF, woF, biasD, bo,
                                      (float*)d_out, hbufD, flagsD);
}

// Round 17
// 4730.542 us; speedup vs baseline: 1.3850x; 1.1754x over previous
//
#include <hip/hip_runtime.h>
#include <stdint.h>

typedef unsigned short u16;
typedef short bf16x8 __attribute__((ext_vector_type(8)));
typedef float f32x4  __attribute__((ext_vector_type(4)));
typedef unsigned short u16x8 __attribute__((ext_vector_type(8)));
typedef unsigned int   u32x4 __attribute__((ext_vector_type(4)));

__device__ __forceinline__ u16 f2bf(float f) {
  uint32_t u = __float_as_uint(f);
  return (u16)((u + 0x7FFFu + ((u >> 16) & 1u)) >> 16);
}
// f32 -> bf16 with 6-bit mantissa (LSB reserved for tag injection)
__device__ __forceinline__ u16 f2bf6(float f) {
  uint32_t u = __float_as_uint(f);
  return (u16)(((u + 0xFFFFu + ((u >> 17) & 1u)) >> 17) << 1);
}
__device__ __forceinline__ float fsig(float x) {
  x = fminf(fmaxf(x, -30.f), 30.f);
  return __builtin_amdgcn_rcpf(1.f + __builtin_amdgcn_exp2f(-1.44269504088896f * x));
}
__device__ __forceinline__ float ftanhf(float x) {
  x = fminf(fmaxf(x, -10.f), 10.f);
  float e = __builtin_amdgcn_exp2f(2.88539008177793f * x);
  return (e - 1.f) * __builtin_amdgcn_rcpf(e + 1.f);
}

// Coherent (cross-XCD) ops: sc0 sc1 => bypass L1/L2, serialize at MALL.
__device__ __forceinline__ int flag_load(const int* p) {
  int v;
  asm volatile("global_load_dword %0, %1, off sc0 sc1\n\ts_waitcnt vmcnt(0)"
               : "=&v"(v) : "v"(p) : "memory");
  return v;
}
__device__ __forceinline__ void flag_store(int* p, int v) {
  asm volatile("global_store_dword %0, %1, off sc0 sc1" :: "v"(p), "v"(v) : "memory");
}
// 4-chunk coherent load: single asm block, waitcnt INSIDE, EARLY-CLOBBER
// outputs ("=&v") so the address pair can never be allocated into an output.
// gfx950 syntax: offset: immediately after `off`, BEFORE cache modifiers.
__device__ __forceinline__ void ld_chunk4(const u16* p, u32x4& a, u32x4& b,
                                          u32x4& c, u32x4& d) {
  asm volatile("global_load_dwordx4 %0, %4, off sc0 sc1\n\t"
               "global_load_dwordx4 %1, %4, off offset:16 sc0 sc1\n\t"
               "global_load_dwordx4 %2, %4, off offset:32 sc0 sc1\n\t"
               "global_load_dwordx4 %3, %4, off offset:48 sc0 sc1\n\t"
               "s_waitcnt vmcnt(0)"
               : "=&v"(a), "=&v"(b), "=&v"(c), "=&v"(d)
               : "v"(p) : "memory");
}
// 16B coherent store; u32x4 ext-vector input (struct inputs don't lower to "v")
__device__ __forceinline__ void st_coh_x4(u16* p, u32x4 v) {
  asm volatile("global_store_dwordx4 %0, %1, off sc0 sc1" :: "v"(p), "v"(v) : "memory");
}
// plain cached 16B load, issue-only (x staging; address never reused after)
__device__ __forceinline__ uint4 ld_x4(const float* p) {
  uint4 v;
  asm volatile("global_load_dwordx4 %0, %1, off" : "=&v"(v) : "v"(p) : "memory");
  return v;
}
__device__ __forceinline__ void wait_vm0() {
  asm volatile("s_waitcnt vmcnt(0)" ::: "memory");
}
// Weight-fragment load via volatile asm: result must stay resident (VGPR/AGPR).
__device__ __forceinline__ bf16x8 pin_frag(const u16* p) {
  u32x4 v;
  asm volatile("global_load_dwordx4 %0, %1, off" : "=&v"(v) : "v"(p));
  return __builtin_bit_cast(bf16x8, v);
}
__device__ __forceinline__ uint32_t nib_of(u32x4 d) {
  return (d[0] & 1u) | ((d[1] & 1u) << 1) | ((d[2] & 1u) << 2) | ((d[3] & 1u) << 3);
}

// ---------------------------------------------------------------------------
// prep: f32 weights -> bf16 MFMA fragment layout, gate-permuted columns;
// zeroes the flag ints AND both h exchange buffers (tag nibble 0 never
// matches 8..15 — replay-stale tags can't alias).
// ---------------------------------------------------------------------------
__global__ void prep_kernel(const float* __restrict__ Wf, const float* __restrict__ Uf, const float* __restrict__ bf,
                            const float* __restrict__ Wb, const float* __restrict__ Ub, const float* __restrict__ bb,
                            const float* __restrict__ Wd, const float* __restrict__ Ud, const float* __restrict__ bd,
                            const float* __restrict__ Wo,
                            u16* __restrict__ encF, u16* __restrict__ encB,
                            u16* __restrict__ udF, u16* __restrict__ wdF, u16* __restrict__ woF,
                            float* __restrict__ biasF, float* __restrict__ biasB, float* __restrict__ biasD,
                            int* __restrict__ flagsAll, u16* __restrict__ hbE, u16* __restrict__ hbD)
{
  constexpr int NC_ENC = 128 * 24 * 64;
  constexpr int NC_UD  = 128 * 16 * 64;
  constexpr int NC_WD  = 128 * 32 * 64;
  constexpr int NC_WO  = 16 * 16 * 64;
  constexpr int B1 = 2 * NC_ENC;
  constexpr int B2 = B1 + NC_UD;
  constexpr int B3 = B2 + NC_WD;
  constexpr int B4 = B3 + NC_WO;
  constexpr int B5 = B4 + 768;
  constexpr int B6 = B5 + 64;          // flags (512 ints / 8)
  constexpr int B7 = B6 + 32768;       // hbE: 16g*16384 u16 / 8
  constexpr int TOTAL = B7 + 16384;    // hbD: 8g*16384 u16 / 8

  for (int idx = blockIdx.x * 256 + threadIdx.x; idx < TOTAL; idx += gridDim.x * 256) {
    if (idx < B1) {
      int d = idx / NC_ENC;
      int r = idx - d * NC_ENC;
      int ntg = r / 1536;
      int rem = r - ntg * 1536;
      int kt = rem >> 6, lane = rem & 63;
      int np = ntg * 16 + (lane & 15);
      int col = (np & 3) * 512 + (np >> 2);
      int kb = kt * 32 + (lane >> 4) * 8;
      const float* W = d ? Wb : Wf;
      const float* U = d ? Ub : Uf;
      u16* dst = (d ? encB : encF) + (size_t)r * 8;
      if (kb < 256) {
        const float* s = W + (size_t)kb * 2048 + col;
#pragma unroll
        for (int e = 0; e < 8; ++e) dst[e] = f2bf(s[(size_t)e * 2048]);
      } else {
        const float* s = U + (size_t)(kb - 256) * 2048 + col;
#pragma unroll
        for (int e = 0; e < 8; ++e) dst[e] = f2bf(s[(size_t)e * 2048]);
      }
    } else if (idx < B2) {
      int r = idx - B1;
      int ntg = r / 1024;
      int rem = r - ntg * 1024;
      int kt = rem >> 6, lane = rem & 63;
      int np = ntg * 16 + (lane & 15);
      int col = (np & 3) * 512 + (np >> 2);
      int kb = kt * 32 + (lane >> 4) * 8;
      const float* s = Ud + (size_t)kb * 2048 + col;
      u16* dst = udF + (size_t)r * 8;
#pragma unroll
      for (int e = 0; e < 8; ++e) dst[e] = f2bf(s[(size_t)e * 2048]);
    } else if (idx < B3) {
      int r = idx - B2;
      int ntg = r / 2048;
      int rem = r - ntg * 2048;
      int kt = rem >> 6, lane = rem & 63;
      int np = ntg * 16 + (lane & 15);
      int col = (np & 3) * 512 + (np >> 2);
      int kb = kt * 32 + (lane >> 4) * 8;
      const float* s = Wd + (size_t)kb * 2048 + col;
      u16* dst = wdF + (size_t)r * 8;
#pragma unroll
      for (int e = 0; e < 8; ++e) dst[e] = f2bf(s[(size_t)e * 2048]);
    } else if (idx < B4) {
      int r = idx - B3;
      int nt = r / 1024;
      int rem = r - nt * 1024;
      int kt = rem >> 6, lane = rem & 63;
      int col = nt * 16 + (lane & 15);
      int kb = kt * 32 + (lane >> 4) * 8;
      const float* s = Wo + (size_t)kb * 256 + col;
      u16* dst = woF + (size_t)r * 8;
#pragma unroll
      for (int e = 0; e < 8; ++e) dst[e] = f2bf(s[(size_t)e * 256]);
    } else if (idx < B5) {
      int r = idx - B4;
      int which = r >> 8;
      int j0 = (r & 255) * 8;
      const float* src = (which == 0) ? bf : (which == 1) ? bb : bd;
      float* dstb = (which == 0) ? biasF : (which == 1) ? biasB : biasD;
#pragma unroll
      for (int e = 0; e < 8; ++e) {
        int np = j0 + e;
        dstb[np] = src[(np & 3) * 512 + (np >> 2)];
      }
    } else if (idx < B6) {
      int r = idx - B5;
#pragma unroll
      for (int e = 0; e < 8; ++e) flagsAll[r * 8 + e] = 0;
    } else if (idx < B7) {
      int r = idx - B6;
      u16x8 z = {0, 0, 0, 0, 0, 0, 0, 0};
      *(u16x8*)&hbE[(size_t)r * 8] = z;
    } else {
      int r = idx - B7;
      u16x8 z = {0, 0, 0, 0, 0, 0, 0, 0};
      *(u16x8*)&hbD[(size_t)r * 8] = z;
    }
  }
}

// ---------------------------------------------------------------------------
// h exchange (per group, per slot of 8192 u16):
//   chunk(b,row) = 8 u16 at u16 offset b*128+row*8; producer wave w of WG wgi
//   owns b = wgi*4+w (one tagged dwordx4 store per lane<16).
//   Tag: LSB of dword j of each chunk = bit j of (8 | (step+1)&7); per-dword
//   tags are tear-proof. Consumer thread tid reads chunks (b=tid>>2, rows
//   (tid&3)*4+k) at hs+8k and polls the DATA; the r14 flag protocol is kept
//   verbatim on the producer as a bounded backstop.
// ---------------------------------------------------------------------------

// encoder: 16 groups (dir=g>>3, rows (g&7)*16..+15), 16 WGs/group, 1 WG/CU.
__global__ __launch_bounds__(256, 1) void enc_kernel(
    const float* __restrict__ x,
    const u16* __restrict__ encF, const u16* __restrict__ encB,
    const float* __restrict__ biasF, const float* __restrict__ biasB,
    float* __restrict__ latent, u16* __restrict__ hbuf, int* __restrict__ flags)
{
  const int bid = blockIdx.x;
  const int g   = bid & 15;
  const int wgi = bid >> 4;
  const int dir = g >> 3;
  const int rowBase = (g & 7) * 16;
  const int tid = threadIdx.x;
  const int lane = tid & 63;
  const int wave = tid >> 6;
  const int l15 = lane & 15;
  const int lk  = lane >> 4;

  __shared__ __attribute__((aligned(16))) u16   xlds[2][16][264];
  __shared__ __attribute__((aligned(16))) u16   Alds[16][520];
  __shared__ __attribute__((aligned(16))) float zlds[4][2][16][20];
  __shared__ __attribute__((aligned(16))) u16   hlds[4][16][8];

  const u16* wsrc = dir ? encB : encF;
  bf16x8 Breg[2][24];
#pragma unroll
  for (int n = 0; n < 2; ++n) {
    const int ntg = wgi * 8 + wave * 2 + n;
    const u16* fb = wsrc + (size_t)(ntg * 1536 + lane) * 8;
#pragma unroll
    for (int kt = 0; kt < 24; ++kt)
      Breg[n][kt] = pin_frag(fb + kt * 512);
  }
  wait_vm0();
  __builtin_amdgcn_sched_barrier(0);

  const float* bias = dir ? biasB : biasF;
  float bias_r[2];
  bias_r[0] = bias[(wgi * 8 + wave * 2 + 0) * 16 + l15];
  bias_r[1] = bias[(wgi * 8 + wave * 2 + 1) * 16 + l15];

  u16* myH = hbuf + (size_t)g * 16384;
  int* myFlags = flags + g * 16;
  const int xr = tid >> 4, xc = tid & 15;       // x staging assignment
  const int cb = tid >> 2;                      // consumer unit-block 0..63
  const int cr0 = (tid & 3) * 4;                // consumer first row

  // prologue: stage x_{t(0)} into xlds[0]
  {
    const int t0 = dir ? 1023 : 0;
    const float* xp = x + ((size_t)(rowBase + xr) * 1024 + t0) * 256 + xc * 16;
    float4 f0 = *(const float4*)xp;
    float4 f1 = *(const float4*)(xp + 4);
    float4 f2 = *(const float4*)(xp + 8);
    float4 f3 = *(const float4*)(xp + 12);
    u16x8 a, b;
    a[0]=f2bf(f0.x); a[1]=f2bf(f0.y); a[2]=f2bf(f0.z); a[3]=f2bf(f0.w);
    a[4]=f2bf(f1.x); a[5]=f2bf(f1.y); a[6]=f2bf(f1.z); a[7]=f2bf(f1.w);
    b[0]=f2bf(f2.x); b[1]=f2bf(f2.y); b[2]=f2bf(f2.z); b[3]=f2bf(f2.w);
    b[4]=f2bf(f3.x); b[5]=f2bf(f3.y); b[6]=f2bf(f3.z); b[7]=f2bf(f3.w);
    *(u16x8*)&xlds[0][xr][xc * 16] = a;
    *(u16x8*)&xlds[0][xr][xc * 16 + 8] = b;
  }
  __syncthreads();

  float cc0 = 0.f, cc1 = 0.f;

  for (int s = 0; s < 1024; ++s) {
    // ---- P1: x-part MFMA from xlds[s&1] ----
    f32x4 acc0 = {bias_r[0], bias_r[0], bias_r[0], bias_r[0]};
    f32x4 acc1 = {bias_r[1], bias_r[1], bias_r[1], bias_r[1]};
#pragma unroll
    for (int kt = 0; kt < 8; ++kt) {
      bf16x8 av = *(const bf16x8*)&xlds[s & 1][l15][kt * 32 + lk * 8];
      acc0 = __builtin_amdgcn_mfma_f32_16x16x32_bf16(av, Breg[0][kt], acc0, 0, 0, 0);
      acc1 = __builtin_amdgcn_mfma_f32_16x16x32_bf16(av, Breg[1][kt], acc1, 0, 0, 0);
    }

    // ---- P0: issue x loads for next step ----
    const int sn = (s + 1 < 1024) ? s + 1 : 1023;
    const int tn = dir ? (1023 - sn) : sn;
    const float* xp = x + ((size_t)(rowBase + xr) * 1024 + tn) * 256 + xc * 16;
    uint4 xq0 = ld_x4(xp);
    uint4 xq1 = ld_x4(xp + 4);
    uint4 xq2 = ld_x4(xp + 8);
    uint4 xq3 = ld_x4(xp + 12);

    // ---- P2: tag-poll the data (flag backstop every 4th iter) ----
    if (s > 0) {
      const uint32_t Texp = 8u | ((uint32_t)s & 7u);
      const u16* hs = myH + ((s - 1) & 1) * 8192 + cb * 128 + cr0 * 8;
      const int* pf = &myFlags[tid >> 4];
      u32x4 h0, h1, h2, h3;
      int it = 0;
      while (true) {
        ld_chunk4(hs, h0, h1, h2, h3);
        if (nib_of(h0) == Texp && nib_of(h1) == Texp &&
            nib_of(h2) == Texp && nib_of(h3) == Texp) break;
        if ((it & 3) == 3 && flag_load(pf) >= s) {
          ld_chunk4(hs, h0, h1, h2, h3);
          break;                 // flag-confirmed: reload is guaranteed valid
        }
        __builtin_amdgcn_s_sleep(1);
        if (++it > 200000) break;   // bounded: wrong answer, not a hang
      }
      h0 &= ~1u; h1 &= ~1u; h2 &= ~1u; h3 &= ~1u;
      *(u32x4*)&Alds[cr0][cb * 8]     = h0;
      *(u32x4*)&Alds[cr0 + 1][cb * 8] = h1;
      *(u32x4*)&Alds[cr0 + 2][cb * 8] = h2;
      *(u32x4*)&Alds[cr0 + 3][cb * 8] = h3;
      __syncthreads();
#pragma unroll
      for (int kt = 0; kt < 16; ++kt) {
        bf16x8 av = *(const bf16x8*)&Alds[l15][kt * 32 + lk * 8];
        acc0 = __builtin_amdgcn_mfma_f32_16x16x32_bf16(av, Breg[0][kt + 8], acc0, 0, 0, 0);
        acc1 = __builtin_amdgcn_mfma_f32_16x16x32_bf16(av, Breg[1][kt + 8], acc1, 0, 0, 0);
      }
    } else {
      wait_vm0();                // drain x loads
      __builtin_amdgcn_sched_barrier(0);
    }

    // ---- P3: transpose gates (wave-local LDS), activations ----
#pragma unroll
    for (int r = 0; r < 4; ++r) {
      zlds[wave][0][lk * 4 + r][l15] = acc0[r];
      zlds[wave][1][lk * 4 + r][l15] = acc1[r];
    }
    asm volatile("s_waitcnt lgkmcnt(0)" ::: "memory");
    float4 g0 = *(const float4*)&zlds[wave][0][l15][lk * 4];
    float4 g1 = *(const float4*)&zlds[wave][1][l15][lk * 4];
    float hv0, hv1;
    { float iv = fsig(g0.x), fv = fsig(g0.y), gg = ftanhf(g0.z), ov = fsig(g0.w);
      cc0 = fv * cc0 + iv * gg;  hv0 = ov * ftanhf(cc0); }
    { float iv = fsig(g1.x), fv = fsig(g1.y), gg = ftanhf(g1.z), ov = fsig(g1.w);
      cc1 = fv * cc1 + iv * gg;  hv1 = ov * ftanhf(cc1); }

    // ---- P4: tag + gather + single 16B coherent store ----
    if (s < 1023) {
      const uint32_t T = 8u | ((uint32_t)(s + 1) & 7u);
      u16 v0, v1;
      if ((lk & 1) == 0) {
        uint32_t b0 = (lk == 0) ? (T & 1u) : ((T >> 1) & 1u);
        uint32_t b1 = (lk == 0) ? ((T >> 2) & 1u) : ((T >> 3) & 1u);
        v0 = f2bf6(hv0) | (u16)b0;
        v1 = f2bf6(hv1) | (u16)b1;
      } else {
        v0 = f2bf(hv0);
        v1 = f2bf(hv1);
      }
      hlds[wave][l15][lk]     = v0;
      hlds[wave][l15][lk + 4] = v1;
      asm volatile("s_waitcnt lgkmcnt(0)" ::: "memory");
      if (lane < 16) {
        const u32x4 c = *(const u32x4*)&hlds[wave][lane][0];
        u16* hw = myH + (s & 1) * 8192 + (wgi * 4 + wave) * 128 + lane * 8;
        st_coh_x4(hw, c);
      }
    } else {
      float* lp = latent + (size_t)(rowBase + l15) * 1024 + dir * 512 + wgi * 32 + wave * 8 + lk;
      lp[0] = hv0;
      lp[4] = hv1;
    }

    // ---- P5: convert + store x for next step (in the store's shadow) ----
    {
      float4 f0 = __builtin_bit_cast(float4, xq0);
      float4 f1 = __builtin_bit_cast(float4, xq1);
      float4 f2 = __builtin_bit_cast(float4, xq2);
      float4 f3 = __builtin_bit_cast(float4, xq3);
      u16x8 a, b;
      a[0]=f2bf(f0.x); a[1]=f2bf(f0.y); a[2]=f2bf(f0.z); a[3]=f2bf(f0.w);
      a[4]=f2bf(f1.x); a[5]=f2bf(f1.y); a[6]=f2bf(f1.z); a[7]=f2bf(f1.w);
      b[0]=f2bf(f2.x); b[1]=f2bf(f2.y); b[2]=f2bf(f2.z); b[3]=f2bf(f2.w);
      b[4]=f2bf(f3.x); b[5]=f2bf(f3.y); b[6]=f2bf(f3.z); b[7]=f2bf(f3.w);
      *(u16x8*)&xlds[(s + 1) & 1][xr][xc * 16] = a;
      *(u16x8*)&xlds[(s + 1) & 1][xr][xc * 16 + 8] = b;
    }

    // ---- release (backstop): drain store, join, raise flag ----
    wait_vm0();
    __syncthreads();
    if (tid == 0 && s < 1023) flag_store(&myFlags[wgi], s + 1);
  }
}

// ---------------------------------------------------------------------------
// decoder: 8 groups x 16 rows, 16 WGs/group (128 WGs). xwd in regs; tagged
// data-poll with flag backstop; Alds double-buffered (no loop-end barrier);
// fused Dense (wave0) after release, off the recurrent chain.
// ---------------------------------------------------------------------------
__global__ __launch_bounds__(256, 1) void dec_kernel(
    const float* __restrict__ latent,
    const u16* __restrict__ udF, const u16* __restrict__ wdF, const u16* __restrict__ woF,
    const float* __restrict__ biasD, const float* __restrict__ bo,
    float* __restrict__ out, u16* __restrict__ hbuf, int* __restrict__ flags)
{
  const int bid = blockIdx.x;      // 0..127
  const int g   = bid & 7;
  const int wgi = bid >> 3;        // 0..15
  const int rowBase = g * 16;
  const int tid = threadIdx.x;
  const int lane = tid & 63;
  const int wave = tid >> 6;
  const int l15 = lane & 15;
  const int lk  = lane >> 4;

  __shared__ __attribute__((aligned(16))) u16   Llds[16][1032];
  __shared__ __attribute__((aligned(16))) u16   Alds[2][16][520];
  __shared__ __attribute__((aligned(16))) float zlds[4][2][16][20];
  __shared__ __attribute__((aligned(16))) u16   hlds[4][16][8];

#pragma unroll
  for (int c8 = 0; c8 < 8; ++c8) {
    const int idx = tid + c8 * 256;
    const int rr = idx >> 7, cf = idx & 127;
    const float* lp = latent + (size_t)(rowBase + rr) * 1024 + cf * 8;
    float4 v0 = *(const float4*)lp;
    float4 v1 = *(const float4*)(lp + 4);
    u16x8 tv;
    tv[0]=f2bf(v0.x); tv[1]=f2bf(v0.y); tv[2]=f2bf(v0.z); tv[3]=f2bf(v0.w);
    tv[4]=f2bf(v1.x); tv[5]=f2bf(v1.y); tv[6]=f2bf(v1.z); tv[7]=f2bf(v1.w);
    *(u16x8*)&Llds[rr][cf * 8] = tv;
  }
  __syncthreads();

  f32x4 xwd[2];
#pragma unroll
  for (int n = 0; n < 2; ++n) {
    const int ntg = wgi * 8 + wave * 2 + n;
    const float br = biasD[ntg * 16 + l15];
    f32x4 xw = {br, br, br, br};
    const u16* wf = wdF + (size_t)(ntg * 2048 + lane) * 8;
#pragma unroll
    for (int kt = 0; kt < 32; ++kt) {
      bf16x8 b = *(const bf16x8*)(wf + kt * 512);
      bf16x8 a = *(const bf16x8*)&Llds[l15][kt * 32 + lk * 8];
      xw = __builtin_amdgcn_mfma_f32_16x16x32_bf16(a, b, xw, 0, 0, 0);
    }
    xwd[n] = xw;
  }

  bf16x8 Bu[2][16];
#pragma unroll
  for (int n = 0; n < 2; ++n) {
    const int ntg = wgi * 8 + wave * 2 + n;
    const u16* ub = udF + (size_t)(ntg * 1024 + lane) * 8;
#pragma unroll
    for (int kt = 0; kt < 16; ++kt)
      Bu[n][kt] = pin_frag(ub + kt * 512);
  }
  bf16x8 Bo[16];
  if (wave == 0) {
    const u16* ob = woF + (size_t)(wgi * 1024 + lane) * 8;
#pragma unroll
    for (int kt = 0; kt < 16; ++kt)
      Bo[kt] = pin_frag(ob + kt * 512);
  }
  wait_vm0();
  __builtin_amdgcn_sched_barrier(0);
  const float bo_r = bo[wgi * 16 + l15];

  u16* myH = hbuf + (size_t)g * 16384;
  int* myFlags = flags + g * 16;
  const int cb = tid >> 2;
  const int cr0 = (tid & 3) * 4;

  float cc0 = 0.f, cc1 = 0.f;

  for (int t = 0; t < 1024; ++t) {
    f32x4 acc0 = xwd[0], acc1 = xwd[1];

    if (t > 0) {
      const uint32_t Texp = 8u | ((uint32_t)t & 7u);
      const u16* hs = myH + ((t - 1) & 1) * 8192 + cb * 128 + cr0 * 8;
      const int* pf = &myFlags[tid >> 4];
      u32x4 h0, h1, h2, h3;
      int it = 0;
      while (true) {
        ld_chunk4(hs, h0, h1, h2, h3);
        if (nib_of(h0) == Texp && nib_of(h1) == Texp &&
            nib_of(h2) == Texp && nib_of(h3) == Texp) break;
        if ((it & 3) == 3 && flag_load(pf) >= t) {
          ld_chunk4(hs, h0, h1, h2, h3);
          break;
        }
        __builtin_amdgcn_s_sleep(1);
        if (++it > 200000) break;
      }
      h0 &= ~1u; h1 &= ~1u; h2 &= ~1u; h3 &= ~1u;
      *(u32x4*)&Alds[t & 1][cr0][cb * 8]     = h0;
      *(u32x4*)&Alds[t & 1][cr0 + 1][cb * 8] = h1;
      *(u32x4*)&Alds[t & 1][cr0 + 2][cb * 8] = h2;
      *(u32x4*)&Alds[t & 1][cr0 + 3][cb * 8] = h3;
      __syncthreads();
#pragma unroll
      for (int kt = 0; kt < 16; ++kt) {
        bf16x8 av = *(const bf16x8*)&Alds[t & 1][l15][kt * 32 + lk * 8];
        acc0 = __builtin_amdgcn_mfma_f32_16x16x32_bf16(av, Bu[0][kt], acc0, 0, 0, 0);
        acc1 = __builtin_amdgcn_mfma_f32_16x16x32_bf16(av, Bu[1][kt], acc1, 0, 0, 0);
      }
    }

#pragma unroll
    for (int r = 0; r < 4; ++r) {
      zlds[wave][0][lk * 4 + r][l15] = acc0[r];
      zlds[wave][1][lk * 4 + r][l15] = acc1[r];
    }
    asm volatile("s_waitcnt lgkmcnt(0)" ::: "memory");
    float4 g0 = *(const float4*)&zlds[wave][0][l15][lk * 4];
    float4 g1 = *(const float4*)&zlds[wave][1][l15][lk * 4];
    float hv0, hv1;
    { float iv = fsig(g0.x), fv = fsig(g0.y), gg = ftanhf(g0.z), ov = fsig(g0.w);
      cc0 = fv * cc0 + iv * gg;  hv0 = ov * ftanhf(cc0); }
    { float iv = fsig(g1.x), fv = fsig(g1.y), gg = ftanhf(g1.z), ov = fsig(g1.w);
      cc1 = fv * cc1 + iv * gg;  hv1 = ov * ftanhf(cc1); }

    // tag + gather + 16B coherent store + drain + join + flag (backstop)
    {
      const uint32_t T = 8u | ((uint32_t)(t + 1) & 7u);
      u16 v0, v1;
      if ((lk & 1) == 0) {
        uint32_t b0 = (lk == 0) ? (T & 1u) : ((T >> 1) & 1u);
        uint32_t b1 = (lk == 0) ? ((T >> 2) & 1u) : ((T >> 3) & 1u);
        v0 = f2bf6(hv0) | (u16)b0;
        v1 = f2bf6(hv1) | (u16)b1;
      } else {
        v0 = f2bf(hv0);
        v1 = f2bf(hv1);
      }
      hlds[wave][l15][lk]     = v0;
      hlds[wave][l15][lk + 4] = v1;
      asm volatile("s_waitcnt lgkmcnt(0)" ::: "memory");
      if (lane < 16) {
        const u32x4 c = *(const u32x4*)&hlds[wave][lane][0];
        u16* hw = myH + (t & 1) * 8192 + (wgi * 4 + wave) * 128 + lane * 8;
        st_coh_x4(hw, c);
      }
      wait_vm0();
      __syncthreads();
      if (tid == 0) flag_store(&myFlags[wgi], t + 1);
    }

    // fused Dense for out[:, t-1, :] — after release, off the chain.
    if (t > 0 && wave == 0) {
      f32x4 od = {bo_r, bo_r, bo_r, bo_r};
#pragma unroll
      for (int kt = 0; kt < 16; ++kt) {
        bf16x8 a = *(const bf16x8*)&Alds[t & 1][l15][kt * 32 + lk * 8];
        od = __builtin_amdgcn_mfma_f32_16x16x32_bf16(a, Bo[kt], od, 0, 0, 0);
      }
#pragma unroll
      for (int r = 0; r < 4; ++r)
        out[((size_t)(rowBase + lk * 4 + r) * 1024 + (t - 1)) * 256 + wgi * 16 + l15] = od[r];
    }
    // no loop-end barrier: Alds double-buffered; zlds/hlds are wave-local
  }

  // out[:, 1023, :] — stage h_1023 into Alds[0] (dense(1023) reads Alds[1])
  {
    const uint32_t Texp = 8u;    // tag of h_1023: 8 | (1024 & 7)
    const u16* hs = myH + 8192 + cb * 128 + cr0 * 8;   // slot 1 = h_1023
    const int* pf = &myFlags[tid >> 4];
    u32x4 h0, h1, h2, h3;
    int it = 0;
    while (true) {
      ld_chunk4(hs, h0, h1, h2, h3);
      if (nib_of(h0) == Texp && nib_of(h1) == Texp &&
          nib_of(h2) == Texp && nib_of(h3) == Texp) break;
      if ((it & 3) == 3 && flag_load(pf) >= 1024) {
        ld_chunk4(hs, h0, h1, h2, h3);
        break;
      }
      __builtin_amdgcn_s_sleep(1);
      if (++it > 200000) break;
    }
    h0 &= ~1u; h1 &= ~1u; h2 &= ~1u; h3 &= ~1u;
    *(u32x4*)&Alds[0][cr0][cb * 8]     = h0;
    *(u32x4*)&Alds[0][cr0 + 1][cb * 8] = h1;
    *(u32x4*)&Alds[0][cr0 + 2][cb * 8] = h2;
    *(u32x4*)&Alds[0][cr0 + 3][cb * 8] = h3;
    __syncthreads();
    if (wave == 0) {
      f32x4 od = {bo_r, bo_r, bo_r, bo_r};
#pragma unroll
      for (int kt = 0; kt < 16; ++kt) {
        bf16x8 a = *(const bf16x8*)&Alds[0][l15][kt * 32 + lk * 8];
        od = __builtin_amdgcn_mfma_f32_16x16x32_bf16(a, Bo[kt], od, 0, 0, 0);
      }
#pragma unroll
      for (int r = 0; r < 4; ++r)
        out[((size_t)(rowBase + lk * 4 + r) * 1024 + 1023) * 256 + wgi * 16 + l15] = od[r];
    }
  }
}

// ---------------------------------------------------------------------------
extern "C" void kernel_launch(void* const* d_in, const int* in_sizes, int n_in,
                              void* d_out, int out_size, void* d_ws, size_t ws_size,
                              hipStream_t stream)
{
  const float* x  = (const float*)d_in[0];
  const float* Wf = (const float*)d_in[1];
  const float* Uf = (const float*)d_in[2];
  const float* bf = (const float*)d_in[3];
  const float* Wb = (const float*)d_in[4];
  const float* Ub = (const float*)d_in[5];
  const float* bb = (const float*)d_in[6];
  const float* Wd = (const float*)d_in[7];
  const float* Ud = (const float*)d_in[8];
  const float* bd = (const float*)d_in[9];
  const float* Wo = (const float*)d_in[10];
  const float* bo = (const float*)d_in[11];

  if (ws_size < 14182400) return;

  char* ws = (char*)d_ws;
  u16*  encF   = (u16*)(ws + 0);
  u16*  encB   = (u16*)(ws + 3145728);
  u16*  udF    = (u16*)(ws + 6291456);
  u16*  wdF    = (u16*)(ws + 8388608);
  u16*  woF    = (u16*)(ws + 12582912);
  float* biasF = (float*)(ws + 12845056);
  float* biasB = (float*)(ws + 12853248);
  float* biasD = (float*)(ws + 12861440);
  float* latent= (float*)(ws + 12869632);
  u16*  hbufE  = (u16*)(ws + 13393920);   // 16 groups * 16384 u16 = 512KB
  u16*  hbufD  = (u16*)(ws + 13918208);   // 8 groups * 16384 u16 = 256KB
  int*  flagsE = (int*)(ws + 14180352);   // 256 ints
  int*  flagsD = (int*)(ws + 14181376);   // 128 ints (prep zeroes 512-int range)

  prep_kernel<<<256, 256, 0, stream>>>(Wf, Uf, bf, Wb, Ub, bb, Wd, Ud, bd, Wo,
                                       encF, encB, udF, wdF, woF,
                                       biasF, biasB, biasD, flagsE, hbufE, hbufD);
  enc_kernel<<<256, 256, 0, stream>>>(x, encF, encB, biasF, biasB, latent, hbufE, flagsE);
  dec_kernel<<<128, 256, 0, stream>>>(latent, udF, wdF, woF, biasD, bo,
                                      (float*)d_out, hbufD, flagsD);
}

// Round 18
// 4716.222 us; speedup vs baseline: 1.3892x; 1.0030x over previous
//
#include <hip/hip_runtime.h>
#include <stdint.h>

typedef unsigned short u16;
typedef short bf16x8 __attribute__((ext_vector_type(8)));
typedef float f32x4  __attribute__((ext_vector_type(4)));
typedef unsigned short u16x8 __attribute__((ext_vector_type(8)));
typedef unsigned int   u32x4 __attribute__((ext_vector_type(4)));

__device__ __forceinline__ u16 f2bf(float f) {
  uint32_t u = __float_as_uint(f);
  return (u16)((u + 0x7FFFu + ((u >> 16) & 1u)) >> 16);
}
// f32 -> bf16 with 6-bit mantissa (LSB reserved for tag injection)
__device__ __forceinline__ u16 f2bf6(float f) {
  uint32_t u = __float_as_uint(f);
  return (u16)(((u + 0xFFFFu + ((u >> 17) & 1u)) >> 17) << 1);
}
__device__ __forceinline__ float fsig(float x) {
  x = fminf(fmaxf(x, -30.f), 30.f);
  return __builtin_amdgcn_rcpf(1.f + __builtin_amdgcn_exp2f(-1.44269504088896f * x));
}
__device__ __forceinline__ float ftanhf(float x) {
  x = fminf(fmaxf(x, -10.f), 10.f);
  float e = __builtin_amdgcn_exp2f(2.88539008177793f * x);
  return (e - 1.f) * __builtin_amdgcn_rcpf(e + 1.f);
}

// Coherent (cross-XCD) ops: sc0 sc1 => bypass L1/L2, serialize at MALL.
// 4-chunk coherent load: single asm block, waitcnt INSIDE, EARLY-CLOBBER
// outputs ("=&v") so the address pair can never be allocated into an output.
__device__ __forceinline__ void ld_chunk4(const u16* p, u32x4& a, u32x4& b,
                                          u32x4& c, u32x4& d) {
  asm volatile("global_load_dwordx4 %0, %4, off sc0 sc1\n\t"
               "global_load_dwordx4 %1, %4, off offset:16 sc0 sc1\n\t"
               "global_load_dwordx4 %2, %4, off offset:32 sc0 sc1\n\t"
               "global_load_dwordx4 %3, %4, off offset:48 sc0 sc1\n\t"
               "s_waitcnt vmcnt(0)"
               : "=&v"(a), "=&v"(b), "=&v"(c), "=&v"(d)
               : "v"(p) : "memory");
}
// 16B coherent store; u32x4 ext-vector input (struct inputs don't lower to "v")
__device__ __forceinline__ void st_coh_x4(u16* p, u32x4 v) {
  asm volatile("global_store_dwordx4 %0, %1, off sc0 sc1" :: "v"(p), "v"(v) : "memory");
}
// plain cached 16B load, issue-only (x staging; drained by ld_chunk4's vmcnt)
__device__ __forceinline__ uint4 ld_x4(const float* p) {
  uint4 v;
  asm volatile("global_load_dwordx4 %0, %1, off" : "=&v"(v) : "v"(p) : "memory");
  return v;
}
__device__ __forceinline__ void wait_vm0() {
  asm volatile("s_waitcnt vmcnt(0)" ::: "memory");
}
// Weight-fragment load via volatile asm: result must stay resident (VGPR/AGPR).
__device__ __forceinline__ bf16x8 pin_frag(const u16* p) {
  u32x4 v;
  asm volatile("global_load_dwordx4 %0, %1, off" : "=&v"(v) : "v"(p));
  return __builtin_bit_cast(bf16x8, v);
}
__device__ __forceinline__ uint32_t nib_of(u32x4 d) {
  return (d[0] & 1u) | ((d[1] & 1u) << 1) | ((d[2] & 1u) << 2) | ((d[3] & 1u) << 3);
}

// ---------------------------------------------------------------------------
// prep: f32 weights -> bf16 MFMA fragment layout, gate-permuted columns;
// zeroes the (legacy) flag ints AND both h exchange buffers (tag nibble 0
// never matches 8..15 — replay-stale tags can't alias).
// ---------------------------------------------------------------------------
__global__ void prep_kernel(const float* __restrict__ Wf, const float* __restrict__ Uf, const float* __restrict__ bf,
                            const float* __restrict__ Wb, const float* __restrict__ Ub, const float* __restrict__ bb,
                            const float* __restrict__ Wd, const float* __restrict__ Ud, const float* __restrict__ bd,
                            const float* __restrict__ Wo,
                            u16* __restrict__ encF, u16* __restrict__ encB,
                            u16* __restrict__ udF, u16* __restrict__ wdF, u16* __restrict__ woF,
                            float* __restrict__ biasF, float* __restrict__ biasB, float* __restrict__ biasD,
                            int* __restrict__ flagsAll, u16* __restrict__ hbE, u16* __restrict__ hbD)
{
  constexpr int NC_ENC = 128 * 24 * 64;
  constexpr int NC_UD  = 128 * 16 * 64;
  constexpr int NC_WD  = 128 * 32 * 64;
  constexpr int NC_WO  = 16 * 16 * 64;
  constexpr int B1 = 2 * NC_ENC;
  constexpr int B2 = B1 + NC_UD;
  constexpr int B3 = B2 + NC_WD;
  constexpr int B4 = B3 + NC_WO;
  constexpr int B5 = B4 + 768;
  constexpr int B6 = B5 + 64;          // flags (512 ints / 8)
  constexpr int B7 = B6 + 32768;       // hbE: 16g*16384 u16 / 8
  constexpr int TOTAL = B7 + 16384;    // hbD: 8g*16384 u16 / 8

  for (int idx = blockIdx.x * 256 + threadIdx.x; idx < TOTAL; idx += gridDim.x * 256) {
    if (idx < B1) {
      int d = idx / NC_ENC;
      int r = idx - d * NC_ENC;
      int ntg = r / 1536;
      int rem = r - ntg * 1536;
      int kt = rem >> 6, lane = rem & 63;
      int np = ntg * 16 + (lane & 15);
      int col = (np & 3) * 512 + (np >> 2);
      int kb = kt * 32 + (lane >> 4) * 8;
      const float* W = d ? Wb : Wf;
      const float* U = d ? Ub : Uf;
      u16* dst = (d ? encB : encF) + (size_t)r * 8;
      if (kb < 256) {
        const float* s = W + (size_t)kb * 2048 + col;
#pragma unroll
        for (int e = 0; e < 8; ++e) dst[e] = f2bf(s[(size_t)e * 2048]);
      } else {
        const float* s = U + (size_t)(kb - 256) * 2048 + col;
#pragma unroll
        for (int e = 0; e < 8; ++e) dst[e] = f2bf(s[(size_t)e * 2048]);
      }
    } else if (idx < B2) {
      int r = idx - B1;
      int ntg = r / 1024;
      int rem = r - ntg * 1024;
      int kt = rem >> 6, lane = rem & 63;
      int np = ntg * 16 + (lane & 15);
      int col = (np & 3) * 512 + (np >> 2);
      int kb = kt * 32 + (lane >> 4) * 8;
      const float* s = Ud + (size_t)kb * 2048 + col;
      u16* dst = udF + (size_t)r * 8;
#pragma unroll
      for (int e = 0; e < 8; ++e) dst[e] = f2bf(s[(size_t)e * 2048]);
    } else if (idx < B3) {
      int r = idx - B2;
      int ntg = r / 2048;
      int rem = r - ntg * 2048;
      int kt = rem >> 6, lane = rem & 63;
      int np = ntg * 16 + (lane & 15);
      int col = (np & 3) * 512 + (np >> 2);
      int kb = kt * 32 + (lane >> 4) * 8;
      const float* s = Wd + (size_t)kb * 2048 + col;
      u16* dst = wdF + (size_t)r * 8;
#pragma unroll
      for (int e = 0; e < 8; ++e) dst[e] = f2bf(s[(size_t)e * 2048]);
    } else if (idx < B4) {
      int r = idx - B3;
      int nt = r / 1024;
      int rem = r - nt * 1024;
      int kt = rem >> 6, lane = rem & 63;
      int col = nt * 16 + (lane & 15);
      int kb = kt * 32 + (lane >> 4) * 8;
      const float* s = Wo + (size_t)kb * 256 + col;
      u16* dst = woF + (size_t)r * 8;
#pragma unroll
      for (int e = 0; e < 8; ++e) dst[e] = f2bf(s[(size_t)e * 256]);
    } else if (idx < B5) {
      int r = idx - B4;
      int which = r >> 8;
      int j0 = (r & 255) * 8;
      const float* src = (which == 0) ? bf : (which == 1) ? bb : bd;
      float* dstb = (which == 0) ? biasF : (which == 1) ? biasB : biasD;
#pragma unroll
      for (int e = 0; e < 8; ++e) {
        int np = j0 + e;
        dstb[np] = src[(np & 3) * 512 + (np >> 2)];
      }
    } else if (idx < B6) {
      int r = idx - B5;
#pragma unroll
      for (int e = 0; e < 8; ++e) flagsAll[r * 8 + e] = 0;
    } else if (idx < B7) {
      int r = idx - B6;
      u16x8 z = {0, 0, 0, 0, 0, 0, 0, 0};
      *(u16x8*)&hbE[(size_t)r * 8] = z;
    } else {
      int r = idx - B7;
      u16x8 z = {0, 0, 0, 0, 0, 0, 0, 0};
      *(u16x8*)&hbD[(size_t)r * 8] = z;
    }
  }
}

// ---------------------------------------------------------------------------
// Pure-tag h exchange (per group, per slot of 8192 u16):
//   chunk(b,row) = 8 u16 at u16 offset b*128+row*8; producer wave w of WG wgi
//   owns b = wgi*4+w (one tagged dwordx4 store per lane<16).
//   Tag: LSB of dword j of each chunk = bit j of (8 | (step+1)&7); per-dword
//   tags are tear-proof. Consumers poll the DATA (no flags).
//   Overwrite safety (transitive): A stores slot t&1 at step t only after A's
//   poll saw every B's h_{t-1} tag; B stored h_{t-1} only after B's reads of
//   slot t&1 (h_{t-2}) completed at the MALL. Same-address MALL serialization
//   orders A's overwrite after B's reads. Skew <= 1 << tag period 8.
// ---------------------------------------------------------------------------

// encoder: 16 groups (dir=g>>3, rows (g&7)*16..+15), 16 WGs/group, 1 WG/CU.
// ONE barrier per step: staging barrier covers Alds[s&1] h-tile AND
// xlds[(s+1)&1] (x converted pre-barrier, read next step post-barrier).
__global__ __launch_bounds__(256, 1) void enc_kernel(
    const float* __restrict__ x,
    const u16* __restrict__ encF, const u16* __restrict__ encB,
    const float* __restrict__ biasF, const float* __restrict__ biasB,
    float* __restrict__ latent, u16* __restrict__ hbuf)
{
  const int bid = blockIdx.x;
  const int g   = bid & 15;
  const int wgi = bid >> 4;
  const int dir = g >> 3;
  const int rowBase = (g & 7) * 16;
  const int tid = threadIdx.x;
  const int lane = tid & 63;
  const int wave = tid >> 6;
  const int l15 = lane & 15;
  const int lk  = lane >> 4;

  __shared__ __attribute__((aligned(16))) u16   xlds[2][16][264];
  __shared__ __attribute__((aligned(16))) u16   Alds[2][16][520];
  __shared__ __attribute__((aligned(16))) float zlds[4][2][16][20];
  __shared__ __attribute__((aligned(16))) u16   hlds[4][16][8];

  const u16* wsrc = dir ? encB : encF;
  bf16x8 Breg[2][24];
#pragma unroll
  for (int n = 0; n < 2; ++n) {
    const int ntg = wgi * 8 + wave * 2 + n;
    const u16* fb = wsrc + (size_t)(ntg * 1536 + lane) * 8;
#pragma unroll
    for (int kt = 0; kt < 24; ++kt)
      Breg[n][kt] = pin_frag(fb + kt * 512);
  }
  wait_vm0();
  __builtin_amdgcn_sched_barrier(0);

  const float* bias = dir ? biasB : biasF;
  float bias_r[2];
  bias_r[0] = bias[(wgi * 8 + wave * 2 + 0) * 16 + l15];
  bias_r[1] = bias[(wgi * 8 + wave * 2 + 1) * 16 + l15];

  u16* myH = hbuf + (size_t)g * 16384;
  const int xr = tid >> 4, xc = tid & 15;       // x staging assignment
  const int cb = tid >> 2;                      // consumer unit-block 0..63
  const int cr0 = (tid & 3) * 4;                // consumer first row

  // prologue: stage x_{t(0)} into xlds[0]
  {
    const int t0 = dir ? 1023 : 0;
    const float* xp = x + ((size_t)(rowBase + xr) * 1024 + t0) * 256 + xc * 16;
    float4 f0 = *(const float4*)xp;
    float4 f1 = *(const float4*)(xp + 4);
    float4 f2 = *(const float4*)(xp + 8);
    float4 f3 = *(const float4*)(xp + 12);
    u16x8 a, b;
    a[0]=f2bf(f0.x); a[1]=f2bf(f0.y); a[2]=f2bf(f0.z); a[3]=f2bf(f0.w);
    a[4]=f2bf(f1.x); a[5]=f2bf(f1.y); a[6]=f2bf(f1.z); a[7]=f2bf(f1.w);
    b[0]=f2bf(f2.x); b[1]=f2bf(f2.y); b[2]=f2bf(f2.z); b[3]=f2bf(f2.w);
    b[4]=f2bf(f3.x); b[5]=f2bf(f3.y); b[6]=f2bf(f3.z); b[7]=f2bf(f3.w);
    *(u16x8*)&xlds[0][xr][xc * 16] = a;
    *(u16x8*)&xlds[0][xr][xc * 16 + 8] = b;
  }
  __syncthreads();

  float cc0 = 0.f, cc1 = 0.f;

  for (int s = 0; s < 1024; ++s) {
    // ---- P1: x-part MFMA from xlds[s&1] ----
    f32x4 acc0 = {bias_r[0], bias_r[0], bias_r[0], bias_r[0]};
    f32x4 acc1 = {bias_r[1], bias_r[1], bias_r[1], bias_r[1]};
#pragma unroll
    for (int kt = 0; kt < 8; ++kt) {
      bf16x8 av = *(const bf16x8*)&xlds[s & 1][l15][kt * 32 + lk * 8];
      acc0 = __builtin_amdgcn_mfma_f32_16x16x32_bf16(av, Breg[0][kt], acc0, 0, 0, 0);
      acc1 = __builtin_amdgcn_mfma_f32_16x16x32_bf16(av, Breg[1][kt], acc1, 0, 0, 0);
    }

    // ---- P0: issue x loads for next step ----
    const int sn = (s + 1 < 1024) ? s + 1 : 1023;
    const int tn = dir ? (1023 - sn) : sn;
    const float* xp = x + ((size_t)(rowBase + xr) * 1024 + tn) * 256 + xc * 16;
    uint4 xq0 = ld_x4(xp);
    uint4 xq1 = ld_x4(xp + 4);
    uint4 xq2 = ld_x4(xp + 8);
    uint4 xq3 = ld_x4(xp + 12);

    // ---- P2: tag-poll h, stage Alds[s&1]; convert x -> xlds[(s+1)&1];
    //      ONE barrier covers both ----
    if (s > 0) {
      const uint32_t Texp = 8u | ((uint32_t)s & 7u);
      const u16* hs = myH + ((s - 1) & 1) * 8192 + cb * 128 + cr0 * 8;
      u32x4 h0, h1, h2, h3;
      int it = 0;
      while (true) {
        ld_chunk4(hs, h0, h1, h2, h3);   // also drains the x loads
        if (nib_of(h0) == Texp && nib_of(h1) == Texp &&
            nib_of(h2) == Texp && nib_of(h3) == Texp) break;
        __builtin_amdgcn_s_sleep(1);
        if (++it > 400000) break;   // bounded: wrong answer, not a hang
      }
      h0 &= ~1u; h1 &= ~1u; h2 &= ~1u; h3 &= ~1u;
      *(u32x4*)&Alds[s & 1][cr0][cb * 8]     = h0;
      *(u32x4*)&Alds[s & 1][cr0 + 1][cb * 8] = h1;
      *(u32x4*)&Alds[s & 1][cr0 + 2][cb * 8] = h2;
      *(u32x4*)&Alds[s & 1][cr0 + 3][cb * 8] = h3;
    } else {
      wait_vm0();                // drain x loads
      __builtin_amdgcn_sched_barrier(0);
    }
    {
      float4 f0 = __builtin_bit_cast(float4, xq0);
      float4 f1 = __builtin_bit_cast(float4, xq1);
      float4 f2 = __builtin_bit_cast(float4, xq2);
      float4 f3 = __builtin_bit_cast(float4, xq3);
      u16x8 a, b;
      a[0]=f2bf(f0.x); a[1]=f2bf(f0.y); a[2]=f2bf(f0.z); a[3]=f2bf(f0.w);
      a[4]=f2bf(f1.x); a[5]=f2bf(f1.y); a[6]=f2bf(f1.z); a[7]=f2bf(f1.w);
      b[0]=f2bf(f2.x); b[1]=f2bf(f2.y); b[2]=f2bf(f2.z); b[3]=f2bf(f2.w);
      b[4]=f2bf(f3.x); b[5]=f2bf(f3.y); b[6]=f2bf(f3.z); b[7]=f2bf(f3.w);
      *(u16x8*)&xlds[(s + 1) & 1][xr][xc * 16] = a;
      *(u16x8*)&xlds[(s + 1) & 1][xr][xc * 16 + 8] = b;
    }
    __syncthreads();             // the ONLY barrier of the step

    // ---- h-part MFMA ----
    if (s > 0) {
#pragma unroll
      for (int kt = 0; kt < 16; ++kt) {
        bf16x8 av = *(const bf16x8*)&Alds[s & 1][l15][kt * 32 + lk * 8];
        acc0 = __builtin_amdgcn_mfma_f32_16x16x32_bf16(av, Breg[0][kt + 8], acc0, 0, 0, 0);
        acc1 = __builtin_amdgcn_mfma_f32_16x16x32_bf16(av, Breg[1][kt + 8], acc1, 0, 0, 0);
      }
    }

    // ---- P3: transpose gates (wave-local LDS), activations ----
#pragma unroll
    for (int r = 0; r < 4; ++r) {
      zlds[wave][0][lk * 4 + r][l15] = acc0[r];
      zlds[wave][1][lk * 4 + r][l15] = acc1[r];
    }
    asm volatile("s_waitcnt lgkmcnt(0)" ::: "memory");
    float4 g0 = *(const float4*)&zlds[wave][0][l15][lk * 4];
    float4 g1 = *(const float4*)&zlds[wave][1][l15][lk * 4];
    float hv0, hv1;
    { float iv = fsig(g0.x), fv = fsig(g0.y), gg = ftanhf(g0.z), ov = fsig(g0.w);
      cc0 = fv * cc0 + iv * gg;  hv0 = ov * ftanhf(cc0); }
    { float iv = fsig(g1.x), fv = fsig(g1.y), gg = ftanhf(g1.z), ov = fsig(g1.w);
      cc1 = fv * cc1 + iv * gg;  hv1 = ov * ftanhf(cc1); }

    // ---- P4: tag + wave-local gather + single 16B coherent store ----
    if (s < 1023) {
      const uint32_t T = 8u | ((uint32_t)(s + 1) & 7u);
      u16 v0, v1;
      if ((lk & 1) == 0) {
        uint32_t b0 = (lk == 0) ? (T & 1u) : ((T >> 1) & 1u);
        uint32_t b1 = (lk == 0) ? ((T >> 2) & 1u) : ((T >> 3) & 1u);
        v0 = f2bf6(hv0) | (u16)b0;
        v1 = f2bf6(hv1) | (u16)b1;
      } else {
        v0 = f2bf(hv0);
        v1 = f2bf(hv1);
      }
      hlds[wave][l15][lk]     = v0;
      hlds[wave][l15][lk + 4] = v1;
      asm volatile("s_waitcnt lgkmcnt(0)" ::: "memory");
      if (lane < 16) {
        const u32x4 c = *(const u32x4*)&hlds[wave][lane][0];
        u16* hw = myH + (s & 1) * 8192 + (wgi * 4 + wave) * 128 + lane * 8;
        st_coh_x4(hw, c);
      }
    } else {
      float* lp = latent + (size_t)(rowBase + l15) * 1024 + dir * 512 + wgi * 32 + wave * 8 + lk;
      lp[0] = hv0;
      lp[4] = hv1;
    }
    // no drain, no release barrier, no flag: tags carry the synchronization
  }
}

// ---------------------------------------------------------------------------
// decoder: 8 groups x 16 rows, 16 WGs/group (128 WGs). xwd in regs; pure-tag
// handoff; Alds double-buffered; ONE barrier per step (staging); fused Dense
// (wave0) after the store, off the recurrent chain.
// ---------------------------------------------------------------------------
__global__ __launch_bounds__(256, 1) void dec_kernel(
    const float* __restrict__ latent,
    const u16* __restrict__ udF, const u16* __restrict__ wdF, const u16* __restrict__ woF,
    const float* __restrict__ biasD, const float* __restrict__ bo,
    float* __restrict__ out, u16* __restrict__ hbuf)
{
  const int bid = blockIdx.x;      // 0..127
  const int g   = bid & 7;
  const int wgi = bid >> 3;        // 0..15
  const int rowBase = g * 16;
  const int tid = threadIdx.x;
  const int lane = tid & 63;
  const int wave = tid >> 6;
  const int l15 = lane & 15;
  const int lk  = lane >> 4;

  __shared__ __attribute__((aligned(16))) u16   Llds[16][1032];
  __shared__ __attribute__((aligned(16))) u16   Alds[2][16][520];
  __shared__ __attribute__((aligned(16))) float zlds[4][2][16][20];
  __shared__ __attribute__((aligned(16))) u16   hlds[4][16][8];

#pragma unroll
  for (int c8 = 0; c8 < 8; ++c8) {
    const int idx = tid + c8 * 256;
    const int rr = idx >> 7, cf = idx & 127;
    const float* lp = latent + (size_t)(rowBase + rr) * 1024 + cf * 8;
    float4 v0 = *(const float4*)lp;
    float4 v1 = *(const float4*)(lp + 4);
    u16x8 tv;
    tv[0]=f2bf(v0.x); tv[1]=f2bf(v0.y); tv[2]=f2bf(v0.z); tv[3]=f2bf(v0.w);
    tv[4]=f2bf(v1.x); tv[5]=f2bf(v1.y); tv[6]=f2bf(v1.z); tv[7]=f2bf(v1.w);
    *(u16x8*)&Llds[rr][cf * 8] = tv;
  }
  __syncthreads();

  f32x4 xwd[2];
#pragma unroll
  for (int n = 0; n < 2; ++n) {
    const int ntg = wgi * 8 + wave * 2 + n;
    const float br = biasD[ntg * 16 + l15];
    f32x4 xw = {br, br, br, br};
    const u16* wf = wdF + (size_t)(ntg * 2048 + lane) * 8;
#pragma unroll
    for (int kt = 0; kt < 32; ++kt) {
      bf16x8 b = *(const bf16x8*)(wf + kt * 512);
      bf16x8 a = *(const bf16x8*)&Llds[l15][kt * 32 + lk * 8];
      xw = __builtin_amdgcn_mfma_f32_16x16x32_bf16(a, b, xw, 0, 0, 0);
    }
    xwd[n] = xw;
  }

  bf16x8 Bu[2][16];
#pragma unroll
  for (int n = 0; n < 2; ++n) {
    const int ntg = wgi * 8 + wave * 2 + n;
    const u16* ub = udF + (size_t)(ntg * 1024 + lane) * 8;
#pragma unroll
    for (int kt = 0; kt < 16; ++kt)
      Bu[n][kt] = pin_frag(ub + kt * 512);
  }
  bf16x8 Bo[16];
  if (wave == 0) {
    const u16* ob = woF + (size_t)(wgi * 1024 + lane) * 8;
#pragma unroll
    for (int kt = 0; kt < 16; ++kt)
      Bo[kt] = pin_frag(ob + kt * 512);
  }
  wait_vm0();
  __builtin_amdgcn_sched_barrier(0);
  const float bo_r = bo[wgi * 16 + l15];

  u16* myH = hbuf + (size_t)g * 16384;
  const int cb = tid >> 2;
  const int cr0 = (tid & 3) * 4;

  float cc0 = 0.f, cc1 = 0.f;

  for (int t = 0; t < 1024; ++t) {
    f32x4 acc0 = xwd[0], acc1 = xwd[1];

    if (t > 0) {
      const uint32_t Texp = 8u | ((uint32_t)t & 7u);
      const u16* hs = myH + ((t - 1) & 1) * 8192 + cb * 128 + cr0 * 8;
      u32x4 h0, h1, h2, h3;
      int it = 0;
      while (true) {
        ld_chunk4(hs, h0, h1, h2, h3);
        if (nib_of(h0) == Texp && nib_of(h1) == Texp &&
            nib_of(h2) == Texp && nib_of(h3) == Texp) break;
        __builtin_amdgcn_s_sleep(1);
        if (++it > 400000) break;
      }
      h0 &= ~1u; h1 &= ~1u; h2 &= ~1u; h3 &= ~1u;
      *(u32x4*)&Alds[t & 1][cr0][cb * 8]     = h0;
      *(u32x4*)&Alds[t & 1][cr0 + 1][cb * 8] = h1;
      *(u32x4*)&Alds[t & 1][cr0 + 2][cb * 8] = h2;
      *(u32x4*)&Alds[t & 1][cr0 + 3][cb * 8] = h3;
      __syncthreads();           // the ONLY barrier of the step
#pragma unroll
      for (int kt = 0; kt < 16; ++kt) {
        bf16x8 av = *(const bf16x8*)&Alds[t & 1][l15][kt * 32 + lk * 8];
        acc0 = __builtin_amdgcn_mfma_f32_16x16x32_bf16(av, Bu[0][kt], acc0, 0, 0, 0);
        acc1 = __builtin_amdgcn_mfma_f32_16x16x32_bf16(av, Bu[1][kt], acc1, 0, 0, 0);
      }
    }

#pragma unroll
    for (int r = 0; r < 4; ++r) {
      zlds[wave][0][lk * 4 + r][l15] = acc0[r];
      zlds[wave][1][lk * 4 + r][l15] = acc1[r];
    }
    asm volatile("s_waitcnt lgkmcnt(0)" ::: "memory");
    float4 g0 = *(const float4*)&zlds[wave][0][l15][lk * 4];
    float4 g1 = *(const float4*)&zlds[wave][1][l15][lk * 4];
    float hv0, hv1;
    { float iv = fsig(g0.x), fv = fsig(g0.y), gg = ftanhf(g0.z), ov = fsig(g0.w);
      cc0 = fv * cc0 + iv * gg;  hv0 = ov * ftanhf(cc0); }
    { float iv = fsig(g1.x), fv = fsig(g1.y), gg = ftanhf(g1.z), ov = fsig(g1.w);
      cc1 = fv * cc1 + iv * gg;  hv1 = ov * ftanhf(cc1); }

    // tag + gather + single 16B coherent store (all steps incl t=1023)
    {
      const uint32_t T = 8u | ((uint32_t)(t + 1) & 7u);
      u16 v0, v1;
      if ((lk & 1) == 0) {
        uint32_t b0 = (lk == 0) ? (T & 1u) : ((T >> 1) & 1u);
        uint32_t b1 = (lk == 0) ? ((T >> 2) & 1u) : ((T >> 3) & 1u);
        v0 = f2bf6(hv0) | (u16)b0;
        v1 = f2bf6(hv1) | (u16)b1;
      } else {
        v0 = f2bf(hv0);
        v1 = f2bf(hv1);
      }
      hlds[wave][l15][lk]     = v0;
      hlds[wave][l15][lk + 4] = v1;
      asm volatile("s_waitcnt lgkmcnt(0)" ::: "memory");
      if (lane < 16) {
        const u32x4 c = *(const u32x4*)&hlds[wave][lane][0];
        u16* hw = myH + (t & 1) * 8192 + (wgi * 4 + wave) * 128 + lane * 8;
        st_coh_x4(hw, c);
      }
    }

    // fused Dense for out[:, t-1, :] — after the store, off the chain.
    if (t > 0 && wave == 0) {
      f32x4 od = {bo_r, bo_r, bo_r, bo_r};
#pragma unroll
      for (int kt = 0; kt < 16; ++kt) {
        bf16x8 a = *(const bf16x8*)&Alds[t & 1][l15][kt * 32 + lk * 8];
        od = __builtin_amdgcn_mfma_f32_16x16x32_bf16(a, Bo[kt], od, 0, 0, 0);
      }
#pragma unroll
      for (int r = 0; r < 4; ++r)
        out[((size_t)(rowBase + lk * 4 + r) * 1024 + (t - 1)) * 256 + wgi * 16 + l15] = od[r];
    }
    // no release barrier / drain / flag: tags carry the synchronization
  }

  // out[:, 1023, :] — stage h_1023 into Alds[0] (dense(1023) reads Alds[1])
  {
    const uint32_t Texp = 8u;    // tag of h_1023: 8 | (1024 & 7)
    const u16* hs = myH + 8192 + cb * 128 + cr0 * 8;   // slot 1 = h_1023
    u32x4 h0, h1, h2, h3;
    int it = 0;
    while (true) {
      ld_chunk4(hs, h0, h1, h2, h3);
      if (nib_of(h0) == Texp && nib_of(h1) == Texp &&
          nib_of(h2) == Texp && nib_of(h3) == Texp) break;
      __builtin_amdgcn_s_sleep(1);
      if (++it > 400000) break;
    }
    h0 &= ~1u; h1 &= ~1u; h2 &= ~1u; h3 &= ~1u;
    *(u32x4*)&Alds[0][cr0][cb * 8]     = h0;
    *(u32x4*)&Alds[0][cr0 + 1][cb * 8] = h1;
    *(u32x4*)&Alds[0][cr0 + 2][cb * 8] = h2;
    *(u32x4*)&Alds[0][cr0 + 3][cb * 8] = h3;
    __syncthreads();
    if (wave == 0) {
      f32x4 od = {bo_r, bo_r, bo_r, bo_r};
#pragma unroll
      for (int kt = 0; kt < 16; ++kt) {
        bf16x8 a = *(const bf16x8*)&Alds[0][l15][kt * 32 + lk * 8];
        od = __builtin_amdgcn_mfma_f32_16x16x32_bf16(a, Bo[kt], od, 0, 0, 0);
      }
#pragma unroll
      for (int r = 0; r < 4; ++r)
        out[((size_t)(rowBase + lk * 4 + r) * 1024 + 1023) * 256 + wgi * 16 + l15] = od[r];
    }
  }
}

// ---------------------------------------------------------------------------
extern "C" void kernel_launch(void* const* d_in, const int* in_sizes, int n_in,
                              void* d_out, int out_size, void* d_ws, size_t ws_size,
                              hipStream_t stream)
{
  const float* x  = (const float*)d_in[0];
  const float* Wf = (const float*)d_in[1];
  const float* Uf = (const float*)d_in[2];
  const float* bf = (const float*)d_in[3];
  const float* Wb = (const float*)d_in[4];
  const float* Ub = (const float*)d_in[5];
  const float* bb = (const float*)d_in[6];
  const float* Wd = (const float*)d_in[7];
  const float* Ud = (const float*)d_in[8];
  const float* bd = (const float*)d_in[9];
  const float* Wo = (const float*)d_in[10];
  const float* bo = (const float*)d_in[11];

  if (ws_size < 14182400) return;

  char* ws = (char*)d_ws;
  u16*  encF   = (u16*)(ws + 0);
  u16*  encB   = (u16*)(ws + 3145728);
  u16*  udF    = (u16*)(ws + 6291456);
  u16*  wdF    = (u16*)(ws + 8388608);
  u16*  woF    = (u16*)(ws + 12582912);
  float* biasF = (float*)(ws + 12845056);
  float* biasB = (float*)(ws + 12853248);
  float* biasD = (float*)(ws + 12861440);
  float* latent= (float*)(ws + 12869632);
  u16*  hbufE  = (u16*)(ws + 13393920);   // 16 groups * 16384 u16 = 512KB
  u16*  hbufD  = (u16*)(ws + 13918208);   // 8 groups * 16384 u16 = 256KB
  int*  flagsE = (int*)(ws + 14180352);   // legacy flags region (still zeroed)

  prep_kernel<<<256, 256, 0, stream>>>(Wf, Uf, bf, Wb, Ub, bb, Wd, Ud, bd, Wo,
                                       encF, encB, udF, wdF, woF,
                                       biasF, biasB, biasD, flagsE, hbufE, hbufD);
  enc_kernel<<<256, 256, 0, stream>>>(x, encF, encB, biasF, biasB, latent, hbufE);
  dec_kernel<<<128, 256, 0, stream>>>(latent, udF, wdF, woF, biasD, bo,
                                      (float*)d_out, hbufD);
}